// Round 2
// baseline (427.424 us; speedup 1.0000x reference)
//
#include <hip/hip_runtime.h>
#include <hip/hip_bf16.h>
#include <math.h>

typedef unsigned short ush;
typedef __attribute__((ext_vector_type(8))) short frag16;   // 8 bf16 = 4 VGPRs
typedef __attribute__((ext_vector_type(4))) float f32x4;

#define S_   1024
#define H_   1024
#define NH_  16
#define D_   64
#define L_   9
#define MB_  (1048576ull)

__device__ __forceinline__ ush bf16_rne(float x) {
  unsigned int b = __float_as_uint(x);
  b += 0x7FFFu + ((b >> 16) & 1u);
  return (ush)(b >> 16);
}
__device__ __forceinline__ void split2(float x, ush& h, ush& l) {
  h = bf16_rne(x);
  l = bf16_rne(x - __uint_as_float((unsigned int)h << 16));
}

// async global->LDS, 16B per lane; lds ptr must be wave-uniform base.
__device__ __forceinline__ void load_lds16(const ush* g, const ush* l) {
  __builtin_amdgcn_global_load_lds(
      (const __attribute__((address_space(1))) void*)g,
      (__attribute__((address_space(3))) void*)l, 16, 0, 0);
}

// ---------------------------------------------------------------------------
// Split + transpose 4 weights in one launch. W [k][n] fp32 -> WTh/WTl [n][k]
// bf16. Grid (16,16,4). (verified R10)
// ---------------------------------------------------------------------------
__global__ __launch_bounds__(256) void split_wT4(
    const float* W0, const float* W1, const float* W2, const float* W3,
    ush* h0, ush* l0, ush* h1, ush* l1, ush* h2, ush* l2, ush* h3, ush* l3) {
  __shared__ __align__(16) float Ls[64][68];
  const float* W = (blockIdx.z == 0) ? W0 : (blockIdx.z == 1) ? W1
                 : (blockIdx.z == 2) ? W2 : W3;
  ush* Th = (blockIdx.z == 0) ? h0 : (blockIdx.z == 1) ? h1
          : (blockIdx.z == 2) ? h2 : h3;
  ush* Tl = (blockIdx.z == 0) ? l0 : (blockIdx.z == 1) ? l1
          : (blockIdx.z == 2) ? l2 : l3;
  const int tid = threadIdx.x;
  const int n0 = blockIdx.x * 64, k0 = blockIdx.y * 64;
#pragma unroll
  for (int it = 0; it < 4; it++) {
    int flat = tid + 256 * it;
    int row = flat >> 4, nc = (flat & 15) * 4;
    *(float4*)&Ls[row][nc] = *(const float4*)&W[(size_t)(k0 + row) * 1024 + n0 + nc];
  }
  __syncthreads();
#pragma unroll
  for (int it = 0; it < 2; it++) {
    int flat = tid + 256 * it;
    int nrow = flat >> 3, kc = (flat & 7) * 8;
    ush hs[8], ls[8];
#pragma unroll
    for (int u = 0; u < 8; u++) split2(Ls[kc + u][nrow], hs[u], ls[u]);
    uint4 ph, pl;
    ph.x = hs[0] | ((unsigned)hs[1] << 16); ph.y = hs[2] | ((unsigned)hs[3] << 16);
    ph.z = hs[4] | ((unsigned)hs[5] << 16); ph.w = hs[6] | ((unsigned)hs[7] << 16);
    pl.x = ls[0] | ((unsigned)ls[1] << 16); pl.y = ls[2] | ((unsigned)ls[3] << 16);
    pl.z = ls[4] | ((unsigned)ls[5] << 16); pl.w = ls[6] | ((unsigned)ls[7] << 16);
    size_t o = (size_t)(n0 + nrow) * 1024 + k0 + kc;
    *(uint4*)&Th[o] = ph;
    *(uint4*)&Tl[o] = pl;
  }
}

// ---------------------------------------------------------------------------
// Pre-split x: fp32 [4096x1024] -> xh, xl bf16 row-major. Grid 2048.
// ---------------------------------------------------------------------------
__global__ __launch_bounds__(256) void split_x(
    const float* __restrict__ x, ush* __restrict__ xh, ush* __restrict__ xl) {
  const size_t i = ((size_t)blockIdx.x * 256 + threadIdx.x) * 8;
  float4 a = *(const float4*)&x[i];
  float4 b = *(const float4*)&x[i + 4];
  const float v[8] = {a.x, a.y, a.z, a.w, b.x, b.y, b.z, b.w};
  ush h[8], l[8];
#pragma unroll
  for (int u = 0; u < 8; u++) split2(v[u], h[u], l[u]);
  uint4 ph, pl;
  ph.x = h[0] | ((unsigned)h[1] << 16); ph.y = h[2] | ((unsigned)h[3] << 16);
  ph.z = h[4] | ((unsigned)h[5] << 16); ph.w = h[6] | ((unsigned)h[7] << 16);
  pl.x = l[0] | ((unsigned)l[1] << 16); pl.y = l[2] | ((unsigned)l[3] << 16);
  pl.z = l[4] | ((unsigned)l[5] << 16); pl.w = l[6] | ((unsigned)l[7] << 16);
  *(uint4*)&xh[i] = ph;
  *(uint4*)&xl[i] = pl;
}

// ---------------------------------------------------------------------------
// m97-structure split-bf16 GEMM: 128(M) x BN(N) tile, BK=32, LINEAR LDS,
// global_load_lds dwordx4 staging. (verified R0 of this session)
// EP: 0 = split bf16 out to head layout, z in {0,1} selects q/k set;
//     1 = bf16 out to head layout (v);
//     2 = fp32 [m][n] + bias + residual (o-proj).
// ---------------------------------------------------------------------------
template <int EP, int BN>
__global__ __launch_bounds__(256) void gemm_big(
    const ush* __restrict__ Ah_g, const ush* __restrict__ Al_g,
    const ush* __restrict__ Bh0, const ush* __restrict__ Bl0,
    const ush* __restrict__ Bh1, const ush* __restrict__ Bl1,
    const float* __restrict__ bias0, const float* __restrict__ bias1,
    const float* __restrict__ resid, float* __restrict__ outf,
    ush* __restrict__ o0h, ush* __restrict__ o0l,
    ush* __restrict__ o1h, ush* __restrict__ o1l) {
  constexpr int NT = BN / 32;                 // frag cols per wave
  __shared__ __align__(16) ush As[2][128][32];  // [hl][m][k] linear
  __shared__ __align__(16) ush Bs[2][BN][32];   // [hl][n][k] linear
  const int tid = threadIdx.x, lane = tid & 63, wave = tid >> 6;
  const int l15 = lane & 15, quad = lane >> 4;
  const int m0 = blockIdx.y * 128, n0 = blockIdx.x * BN;

  const int z = (EP == 0) ? blockIdx.z : 0;
  const ush* Bh_g = z ? Bh1 : Bh0;
  const ush* Bl_g = z ? Bl1 : Bl0;
  const float* bias = z ? bias1 : bias0;
  ush* ohp = z ? o1h : o0h;
  ush* olp = z ? o1l : o0l;

  const int wm = (wave >> 1) * 64, wn = (wave & 1) * (BN / 2);

  f32x4 acc[4][NT];
#pragma unroll
  for (int i = 0; i < 4; i++)
#pragma unroll
    for (int j = 0; j < NT; j++) acc[i][j] = (f32x4){0.f, 0.f, 0.f, 0.f};

  for (int k0 = 0; k0 < 1024; k0 += 32) {
#pragma unroll
    for (int jj = 0; jj < 4; jj++) {
      const int call = wave * 4 + jj;
      const int c = call * 64 + lane;               // chunk id
      const int r = (c >> 2) & 127, ch = c & 3;     // row / 16B-chunk in row
      const ush* src = ((c >> 9) ? Al_g : Ah_g)
                     + (size_t)(m0 + r) * 1024 + k0 + ch * 8;
      load_lds16(src, &As[0][0][0] + (size_t)call * 512);  // 512 ush = 1KB
    }
#pragma unroll
    for (int jj = 0; jj < NT; jj++) {
      const int call = wave * NT + jj;
      const int c = call * 64 + lane;
      const int r = (c >> 2) & (BN - 1), ch = c & 3;
      const ush* src = ((c >= BN * 4) ? Bl_g : Bh_g)
                     + (size_t)(n0 + r) * 1024 + k0 + ch * 8;
      load_lds16(src, &Bs[0][0][0] + (size_t)call * 512);
    }
    __syncthreads();   // drains vmcnt -> staged data visible

    frag16 a_h[4], a_l[4], b_h[NT], b_l[NT];
#pragma unroll
    for (int s = 0; s < 4; s++) {
      const int row = wm + s * 16 + l15;
      a_h[s] = *(const frag16*)&As[0][row][quad * 8];
      a_l[s] = *(const frag16*)&As[1][row][quad * 8];
    }
#pragma unroll
    for (int t = 0; t < NT; t++) {
      const int col = wn + t * 16 + l15;
      b_h[t] = *(const frag16*)&Bs[0][col][quad * 8];
      b_l[t] = *(const frag16*)&Bs[1][col][quad * 8];
    }
#pragma unroll
    for (int mi = 0; mi < 4; mi++)
#pragma unroll
      for (int ni = 0; ni < NT; ni++) {
        acc[mi][ni] = __builtin_amdgcn_mfma_f32_16x16x32_bf16(
            a_h[mi], b_h[ni], acc[mi][ni], 0, 0, 0);
        acc[mi][ni] = __builtin_amdgcn_mfma_f32_16x16x32_bf16(
            a_h[mi], b_l[ni], acc[mi][ni], 0, 0, 0);
        acc[mi][ni] = __builtin_amdgcn_mfma_f32_16x16x32_bf16(
            a_l[mi], b_h[ni], acc[mi][ni], 0, 0, 0);
      }
    __syncthreads();
  }

#pragma unroll
  for (int mi = 0; mi < 4; mi++) {
    const int rbase = m0 + wm + mi * 16 + quad * 4;
#pragma unroll
    for (int ni = 0; ni < NT; ni++) {
      const int col = n0 + wn + ni * 16 + l15;
      const float bv = bias[col];
      const int hidx = col >> 6, d = col & 63;
#pragma unroll
      for (int r = 0; r < 4; r++) {
        const int m = rbase + r;
        float val = acc[mi][ni][r] + bv;
        if (EP == 2) {
          outf[(size_t)m * 1024 + col] = val + resid[(size_t)m * 1024 + col];
        } else {
          const int bb = m >> 10, ss = m & 1023;
          const size_t o = ((size_t)(bb * NH_ + hidx) * S_ + ss) * D_ + d;
          if (EP == 0) {
            ush hh, ll;
            split2(val, hh, ll);
            ohp[o] = hh;
            olp[o] = ll;
          } else {
            ohp[o] = bf16_rne(val);
          }
        }
      }
    }
  }
}

// ---------------------------------------------------------------------------
// V transpose: vbf [bh][s][d] bf16 -> vT [bh][d][s] bf16. (verified R10)
// ---------------------------------------------------------------------------
__global__ __launch_bounds__(256) void transpose_v(
    const ush* __restrict__ vbf, ush* __restrict__ vT) {
  __shared__ __align__(16) ush Ls[64][72];
  const int tid = threadIdx.x;
  const int s0 = blockIdx.x * 64, bh = blockIdx.y;
#pragma unroll
  for (int it = 0; it < 2; it++) {
    int flat = tid + 256 * it;
    int row = flat >> 3, dc = (flat & 7) * 8;
    *(uint4*)&Ls[row][dc] =
        *(const uint4*)&vbf[((size_t)bh * S_ + s0 + row) * D_ + dc];
  }
  __syncthreads();
#pragma unroll
  for (int it = 0; it < 2; it++) {
    int flat = tid + 256 * it;
    int drow = flat >> 3, sc = (flat & 7) * 8;
    ush v8[8];
#pragma unroll
    for (int u = 0; u < 8; u++) v8[u] = Ls[sc + u][drow];
    uint4 p;
    p.x = v8[0] | ((unsigned)v8[1] << 16); p.y = v8[2] | ((unsigned)v8[3] << 16);
    p.z = v8[4] | ((unsigned)v8[5] << 16); p.w = v8[6] | ((unsigned)v8[7] << 16);
    *(uint4*)&vT[((size_t)bh * D_ + drow) * S_ + s0 + sc] = p;
  }
}

// ---------------------------------------------------------------------------
// MFMA flash attention, barrier-free: K/V fragments read DIRECTLY from
// global (L2-resident: K+V = 384KB/head, re-read 16x -> L2 hits; staging
// through LDS was pure overhead, cf. m169). Only Pst (wave-private P
// transpose buffer) stays in LDS -> zero __syncthreads in the kernel.
// Fixed-max softmax (M=20, shift-invariant exact), far-tile path in exp2
// domain (1 transcendental + 2 fma/elem, abs as free input modifier).
// LDS 9216 B; launch_bounds(256,4) caps VGPR at 128 -> >=4 blocks/CU.
// ---------------------------------------------------------------------------
__global__ __launch_bounds__(256, 4) void attn2(
    const ush* __restrict__ qh, const ush* __restrict__ ql,
    const ush* __restrict__ kh, const ush* __restrict__ kl,
    const ush* __restrict__ vT,
    ush* __restrict__ ch, ush* __restrict__ cl) {
  __shared__ __align__(16) ush Pst[64][72];   // [m][j], wave-private rows
  const int tid = threadIdx.x;
  const int lane = tid & 63, wave = tid >> 6;
  const int l15 = lane & 15, quad = lane >> 4;
  const int w16 = wave * 16;
  const int bh = blockIdx.y;
  const int b = bh >> 4, h = bh & 15;
  const int q0 = blockIdx.x * 64;

  // ---- Q fragments straight from global (A-layout: m=l15, k=quad*8+j) ----
  const size_t qrow = ((size_t)bh * S_ + q0 + w16 + l15) * D_;
  frag16 a_h[2], a_l[2];
  a_h[0] = *(const frag16*)&qh[qrow + quad * 8];
  a_h[1] = *(const frag16*)&qh[qrow + 32 + quad * 8];
  a_l[0] = *(const frag16*)&ql[qrow + quad * 8];
  a_l[1] = *(const frag16*)&ql[qrow + 32 + quad * 8];

  f32x4 o[4];
  float lrow[4];
#pragma unroll
  for (int i = 0; i < 4; i++) {
    o[i] = (f32x4){0.f, 0.f, 0.f, 0.f};
    lrow[i] = 0.f;
  }

  // exp2-domain constants: exp(x) = exp2(x*log2e)
  const float K1 = 0.18033688011112042f;   // 0.125 * log2(e)
  const float K2 = 0.14426950408889634f;   // 0.1   * log2(e)
  // far-tile: pb = exp(-0.5) constant -> fold (pb*0.125 - 20)*log2e
  const float CF = -28.853900817779268f + 0.60653066f * K1;

  const size_t kbase = (size_t)bh * S_ * D_;
  const size_t vbase = (size_t)bh * D_ * S_;

  for (int j0 = 0; j0 < S_; j0 += 64) {
    // ---- S = Q.K^T (3-term split), K frags direct from global ----
    f32x4 c4[4];
#pragma unroll
    for (int nt = 0; nt < 4; nt++) c4[nt] = (f32x4){0.f, 0.f, 0.f, 0.f};
#pragma unroll
    for (int nt = 0; nt < 4; nt++) {
      const size_t krow = kbase + (size_t)(j0 + nt * 16 + l15) * D_;
      frag16 bh0 = *(const frag16*)&kh[krow + quad * 8];
      frag16 bh1 = *(const frag16*)&kh[krow + 32 + quad * 8];
      frag16 bl0 = *(const frag16*)&kl[krow + quad * 8];
      frag16 bl1 = *(const frag16*)&kl[krow + 32 + quad * 8];
      c4[nt] = __builtin_amdgcn_mfma_f32_16x16x32_bf16(a_h[0], bh0, c4[nt], 0, 0, 0);
      c4[nt] = __builtin_amdgcn_mfma_f32_16x16x32_bf16(a_h[1], bh1, c4[nt], 0, 0, 0);
      c4[nt] = __builtin_amdgcn_mfma_f32_16x16x32_bf16(a_l[0], bh0, c4[nt], 0, 0, 0);
      c4[nt] = __builtin_amdgcn_mfma_f32_16x16x32_bf16(a_l[1], bh1, c4[nt], 0, 0, 0);
      c4[nt] = __builtin_amdgcn_mfma_f32_16x16x32_bf16(a_h[0], bl0, c4[nt], 0, 0, 0);
      c4[nt] = __builtin_amdgcn_mfma_f32_16x16x32_bf16(a_h[1], bl1, c4[nt], 0, 0, 0);
    }

    // ---- bias + fixed-max exp + P store (C-layout: row=quad*4+r) ----
    const bool far = (j0 >= q0 + 68) || (q0 >= j0 + 68);
    const float fb = (float)(q0 + w16 + quad * 4 - j0 - l15);
#pragma unroll
    for (int r = 0; r < 4; r++) {
#pragma unroll
      for (int nt = 0; nt < 4; nt++) {
        const float df = fb + (float)r - 16.0f * (float)nt;   // qi - jj
        const float dist = fabsf(df);
        float sv;
        if (far) {
          sv = exp2f(fmaf(c4[nt][r], K1, fmaf(dist, -K2, CF)));
        } else {
          const float pb = __expf(-0.1f * fminf(dist, 5.0f));
          sv = __expf((c4[nt][r] + pb) * 0.125f - 0.1f * dist - 20.0f);
        }
        lrow[r] += sv;
        Pst[w16 + quad * 4 + r][nt * 16 + l15] = bf16_rne(sv);
      }
    }

    // ---- PV (own rows only; same-wave LDS ordering, no barrier),
    //      V^T frags direct from global ----
    frag16 pa[2];
    pa[0] = *(const frag16*)&Pst[w16 + l15][quad * 8];
    pa[1] = *(const frag16*)&Pst[w16 + l15][32 + quad * 8];
#pragma unroll
    for (int dt = 0; dt < 4; dt++) {
      const size_t vrow = vbase + (size_t)(dt * 16 + l15) * S_ + j0;
      frag16 vb0 = *(const frag16*)&vT[vrow + quad * 8];
      frag16 vb1 = *(const frag16*)&vT[vrow + 32 + quad * 8];
      o[dt] = __builtin_amdgcn_mfma_f32_16x16x32_bf16(pa[0], vb0, o[dt], 0, 0, 0);
      o[dt] = __builtin_amdgcn_mfma_f32_16x16x32_bf16(pa[1], vb1, o[dt], 0, 0, 0);
    }
  }

  // ---- deferred row-sum reduction + normalize + write pre-split ctx ----
#pragma unroll
  for (int r = 0; r < 4; r++) {
#pragma unroll
    for (int off = 1; off < 16; off <<= 1) lrow[r] += __shfl_xor(lrow[r], off);
    const float inv = 1.0f / lrow[r];
    const size_t rowp =
        ((size_t)(b * S_ + q0 + w16 + quad * 4 + r)) * H_ + h * 64;
#pragma unroll
    for (int dt = 0; dt < 4; dt++) {
      ush hh, ll;
      split2(o[dt][r] * inv, hh, ll);
      ch[rowp + dt * 16 + l15] = hh;
      cl[rowp + dt * 16 + l15] = ll;
    }
  }
}

// ---------------------------------------------------------------------------
// Fused LayerNorm + span logits: one block per row. (verified R10)
// ---------------------------------------------------------------------------
__global__ __launch_bounds__(256) void ln_span(
    const float* __restrict__ y, const float* __restrict__ g,
    const float* __restrict__ bta, const float* __restrict__ Wsp,
    const float* __restrict__ bs, float* __restrict__ logits) {
  const int row = blockIdx.x;
  const int tid = threadIdx.x, lane = tid & 63, wave = tid >> 6;
  const float* yr = y + (size_t)row * 1024;
  float vals[4], s = 0.f, s2 = 0.f;
#pragma unroll
  for (int i = 0; i < 4; i++) {
    float t = yr[tid + i * 256];
    vals[i] = t; s += t; s2 += t * t;
  }
#pragma unroll
  for (int off = 32; off; off >>= 1) {
    s += __shfl_xor(s, off);
    s2 += __shfl_xor(s2, off);
  }
  __shared__ float red[8];
  __shared__ float red9[4][12];
  if (lane == 0) { red[wave] = s; red[4 + wave] = s2; }
  __syncthreads();
  s = red[0] + red[1] + red[2] + red[3];
  s2 = red[4] + red[5] + red[6] + red[7];
  const float mu = s * (1.0f / 1024.0f);
  const float var = s2 * (1.0f / 1024.0f) - mu * mu;
  const float inv = rsqrtf(var + 1e-5f);

  float lg[9];
#pragma unroll
  for (int l = 0; l < 9; l++) lg[l] = 0.f;
#pragma unroll
  for (int i = 0; i < 4; i++) {
    const int hh = tid + i * 256;
    const float yn = (vals[i] - mu) * inv * g[hh] + bta[hh];
#pragma unroll
    for (int l = 0; l < 9; l++) lg[l] += yn * Wsp[hh * 9 + l];
  }
#pragma unroll
  for (int l = 0; l < 9; l++) {
#pragma unroll
    for (int off = 32; off; off >>= 1) lg[l] += __shfl_xor(lg[l], off);
  }
  if (lane == 0) {
#pragma unroll
    for (int l = 0; l < 9; l++) red9[wave][l] = lg[l];
  }
  __syncthreads();
  if (tid < 9) {
    logits[(size_t)row * 9 + tid] =
        red9[0][tid] + red9[1][tid] + red9[2][tid] + red9[3][tid] + bs[tid];
  }
}

// ---------------------------------------------------------------------------
// Entity-bias adjustment + FP32 output. One thread per token.
// ---------------------------------------------------------------------------
__global__ __launch_bounds__(256) void final_kernel(
    const float* __restrict__ logits, const float* __restrict__ eb,
    float* __restrict__ out) {
  const int m = blockIdx.x * 256 + threadIdx.x;
  const int i = m & 1023;
  float cur[9];
#pragma unroll
  for (int l = 0; l < 9; l++) cur[l] = logits[(size_t)m * 9 + l];
  if (i > 0) {
    const float* prev = logits + (size_t)(m - 1) * 9;
    int am = 0;
    float best = prev[0];
#pragma unroll
    for (int l = 1; l < 9; l++) {
      float pv = prev[l];
      if (pv > best) { best = pv; am = l; }
    }
    if (am == 1) cur[2] += 2.0f * eb[2];
  }
#pragma unroll
  for (int l = 0; l < 9; l++) out[(size_t)m * 9 + l] = cur[l];
}

// ---------------------------------------------------------------------------
extern "C" void kernel_launch(void* const* d_in, const int* in_sizes, int n_in,
                              void* d_out, int out_size, void* d_ws, size_t ws_size,
                              hipStream_t stream) {
  const float* x    = (const float*)d_in[0];
  const float* Wq   = (const float*)d_in[1];
  const float* bq   = (const float*)d_in[2];
  const float* Wk   = (const float*)d_in[3];
  const float* bk   = (const float*)d_in[4];
  const float* Wv   = (const float*)d_in[5];
  const float* bv   = (const float*)d_in[6];
  const float* Wo   = (const float*)d_in[7];
  const float* bo   = (const float*)d_in[8];
  const float* ln_g = (const float*)d_in[9];
  const float* ln_b = (const float*)d_in[10];
  const float* Ws   = (const float*)d_in[11];
  const float* bs   = (const float*)d_in[12];
  const float* eb   = (const float*)d_in[13];
  float* out = (float*)d_out;
  char* W8 = (char*)d_ws;

  // ---- ws layout, 64 MB envelope with phase-aliasing ----
  ush* WoT_h = (ush*)(W8 + 0 * MB_);
  ush* WoT_l = (ush*)(W8 + 2 * MB_);
  ush* WqT_h = (ush*)(W8 + 4 * MB_);
  ush* WqT_l = (ush*)(W8 + 6 * MB_);
  ush* WkT_h = (ush*)(W8 + 8 * MB_);
  ush* WkT_l = (ush*)(W8 + 10 * MB_);
  ush* WvT_h = (ush*)(W8 + 12 * MB_);
  ush* WvT_l = (ush*)(W8 + 14 * MB_);
  ush* xh    = (ush*)(W8 + 16 * MB_);
  ush* xl    = (ush*)(W8 + 24 * MB_);
  ush* qh    = (ush*)(W8 + 32 * MB_);
  ush* ql    = (ush*)(W8 + 40 * MB_);
  ush* kh    = (ush*)(W8 + 48 * MB_);
  ush* kl    = (ush*)(W8 + 56 * MB_);
  // aliases:
  ush*   vbf  = (ush*)(W8 + 4 * MB_);    // over WqT+WkT (dead after qk dispatch), 8 MB
  ush*   vT   = (ush*)(W8 + 16 * MB_);   // over xh (dead after v-gemm)
  ush*   ctxh = (ush*)(W8 + 24 * MB_);   // over xl (dead)
  ush*   ctxl = (ush*)(W8 + 4 * MB_);    // over vbf (dead after transpose)
  float* y_ws = (float*)(W8 + 32 * MB_); // over qh/ql (dead after attn)
  float* lg_ws = (float*)(W8 + 48 * MB_);// over kh (dead after attn)

  split_wT4<<<dim3(16, 16, 4), 256, 0, stream>>>(
      Wq, Wk, Wv, Wo, WqT_h, WqT_l, WkT_h, WkT_l, WvT_h, WvT_l, WoT_h, WoT_l);
  split_x<<<2048, 256, 0, stream>>>(x, xh, xl);

  // Q+K fused: z selects {Wq->qh/ql, Wk->kh/kl}. 512 blocks = 2/CU.
  gemm_big<0, 128><<<dim3(8, 32, 2), 256, 0, stream>>>(
      xh, xl, WqT_h, WqT_l, WkT_h, WkT_l, bq, bk,
      nullptr, nullptr, qh, ql, kh, kl);
  // V (after qk so vbf can alias dead WqT/WkT). 512 blocks = 2/CU.
  gemm_big<1, 64><<<dim3(16, 32), 256, 0, stream>>>(
      xh, xl, WvT_h, WvT_l, nullptr, nullptr, bv, nullptr,
      nullptr, nullptr, vbf, nullptr, nullptr, nullptr);
  transpose_v<<<dim3(16, 64), 256, 0, stream>>>(vbf, vT);
  attn2<<<dim3(16, 64), 256, 0, stream>>>(qh, ql, kh, kl, vT, ctxh, ctxl);
  // O-proj + residual. 512 blocks = 2/CU.
  gemm_big<2, 64><<<dim3(16, 32), 256, 0, stream>>>(
      ctxh, ctxl, WoT_h, WoT_l, nullptr, nullptr, bo, nullptr,
      x, y_ws, nullptr, nullptr, nullptr, nullptr);
  ln_span<<<4096, 256, 0, stream>>>(y_ws, ln_g, ln_b, Ws, bs, lg_ws);
  final_kernel<<<16, 256, 0, stream>>>(lg_ws, eb, out);
}

// Round 3
// 300.254 us; speedup vs baseline: 1.4235x; 1.4235x over previous
//
#include <hip/hip_runtime.h>
#include <hip/hip_bf16.h>
#include <math.h>

typedef unsigned short ush;
typedef __attribute__((ext_vector_type(8))) short frag16;   // 8 bf16 = 4 VGPRs
typedef __attribute__((ext_vector_type(4))) float f32x4;

#define S_   1024
#define H_   1024
#define NH_  16
#define D_   64
#define L_   9
#define MB_  (1048576ull)

__device__ __forceinline__ ush bf16_rne(float x) {
  unsigned int b = __float_as_uint(x);
  b += 0x7FFFu + ((b >> 16) & 1u);
  return (ush)(b >> 16);
}
__device__ __forceinline__ void split2(float x, ush& h, ush& l) {
  h = bf16_rne(x);
  l = bf16_rne(x - __uint_as_float((unsigned int)h << 16));
}

// async global->LDS, 16B per lane; lds ptr must be wave-uniform base.
__device__ __forceinline__ void load_lds16(const ush* g, const ush* l) {
  __builtin_amdgcn_global_load_lds(
      (const __attribute__((address_space(1))) void*)g,
      (__attribute__((address_space(3))) void*)l, 16, 0, 0);
}

// ---------------------------------------------------------------------------
// Split + transpose 4 weights in one launch. W [k][n] fp32 -> WTh/WTl [n][k]
// bf16. Grid (16,16,4). (verified R10)
// ---------------------------------------------------------------------------
__global__ __launch_bounds__(256) void split_wT4(
    const float* W0, const float* W1, const float* W2, const float* W3,
    ush* h0, ush* l0, ush* h1, ush* l1, ush* h2, ush* l2, ush* h3, ush* l3) {
  __shared__ __align__(16) float Ls[64][68];
  const float* W = (blockIdx.z == 0) ? W0 : (blockIdx.z == 1) ? W1
                 : (blockIdx.z == 2) ? W2 : W3;
  ush* Th = (blockIdx.z == 0) ? h0 : (blockIdx.z == 1) ? h1
          : (blockIdx.z == 2) ? h2 : h3;
  ush* Tl = (blockIdx.z == 0) ? l0 : (blockIdx.z == 1) ? l1
          : (blockIdx.z == 2) ? l2 : l3;
  const int tid = threadIdx.x;
  const int n0 = blockIdx.x * 64, k0 = blockIdx.y * 64;
#pragma unroll
  for (int it = 0; it < 4; it++) {
    int flat = tid + 256 * it;
    int row = flat >> 4, nc = (flat & 15) * 4;
    *(float4*)&Ls[row][nc] = *(const float4*)&W[(size_t)(k0 + row) * 1024 + n0 + nc];
  }
  __syncthreads();
#pragma unroll
  for (int it = 0; it < 2; it++) {
    int flat = tid + 256 * it;
    int nrow = flat >> 3, kc = (flat & 7) * 8;
    ush hs[8], ls[8];
#pragma unroll
    for (int u = 0; u < 8; u++) split2(Ls[kc + u][nrow], hs[u], ls[u]);
    uint4 ph, pl;
    ph.x = hs[0] | ((unsigned)hs[1] << 16); ph.y = hs[2] | ((unsigned)hs[3] << 16);
    ph.z = hs[4] | ((unsigned)hs[5] << 16); ph.w = hs[6] | ((unsigned)hs[7] << 16);
    pl.x = ls[0] | ((unsigned)ls[1] << 16); pl.y = ls[2] | ((unsigned)ls[3] << 16);
    pl.z = ls[4] | ((unsigned)ls[5] << 16); pl.w = ls[6] | ((unsigned)ls[7] << 16);
    size_t o = (size_t)(n0 + nrow) * 1024 + k0 + kc;
    *(uint4*)&Th[o] = ph;
    *(uint4*)&Tl[o] = pl;
  }
}

// ---------------------------------------------------------------------------
// Pre-split x: fp32 [4096x1024] -> xh, xl bf16 row-major. Grid 2048.
// ---------------------------------------------------------------------------
__global__ __launch_bounds__(256) void split_x(
    const float* __restrict__ x, ush* __restrict__ xh, ush* __restrict__ xl) {
  const size_t i = ((size_t)blockIdx.x * 256 + threadIdx.x) * 8;
  float4 a = *(const float4*)&x[i];
  float4 b = *(const float4*)&x[i + 4];
  const float v[8] = {a.x, a.y, a.z, a.w, b.x, b.y, b.z, b.w};
  ush h[8], l[8];
#pragma unroll
  for (int u = 0; u < 8; u++) split2(v[u], h[u], l[u]);
  uint4 ph, pl;
  ph.x = h[0] | ((unsigned)h[1] << 16); ph.y = h[2] | ((unsigned)h[3] << 16);
  ph.z = h[4] | ((unsigned)h[5] << 16); ph.w = h[6] | ((unsigned)h[7] << 16);
  pl.x = l[0] | ((unsigned)l[1] << 16); pl.y = l[2] | ((unsigned)l[3] << 16);
  pl.z = l[4] | ((unsigned)l[5] << 16); pl.w = l[6] | ((unsigned)l[7] << 16);
  *(uint4*)&xh[i] = ph;
  *(uint4*)&xl[i] = pl;
}

// ---------------------------------------------------------------------------
// m97-structure split-bf16 GEMM: 128(M) x BN(N) tile, BK=32, LINEAR LDS,
// global_load_lds dwordx4 staging. (verified R0 of this session)
// EP: 0 = split bf16 out to head layout, z in {0,1} selects q/k set;
//     1 = bf16 out to head layout (v);
//     2 = fp32 [m][n] + bias + residual (o-proj).
// ---------------------------------------------------------------------------
template <int EP, int BN>
__global__ __launch_bounds__(256) void gemm_big(
    const ush* __restrict__ Ah_g, const ush* __restrict__ Al_g,
    const ush* __restrict__ Bh0, const ush* __restrict__ Bl0,
    const ush* __restrict__ Bh1, const ush* __restrict__ Bl1,
    const float* __restrict__ bias0, const float* __restrict__ bias1,
    const float* __restrict__ resid, float* __restrict__ outf,
    ush* __restrict__ o0h, ush* __restrict__ o0l,
    ush* __restrict__ o1h, ush* __restrict__ o1l) {
  constexpr int NT = BN / 32;                 // frag cols per wave
  __shared__ __align__(16) ush As[2][128][32];  // [hl][m][k] linear
  __shared__ __align__(16) ush Bs[2][BN][32];   // [hl][n][k] linear
  const int tid = threadIdx.x, lane = tid & 63, wave = tid >> 6;
  const int l15 = lane & 15, quad = lane >> 4;
  const int m0 = blockIdx.y * 128, n0 = blockIdx.x * BN;

  const int z = (EP == 0) ? blockIdx.z : 0;
  const ush* Bh_g = z ? Bh1 : Bh0;
  const ush* Bl_g = z ? Bl1 : Bl0;
  const float* bias = z ? bias1 : bias0;
  ush* ohp = z ? o1h : o0h;
  ush* olp = z ? o1l : o0l;

  const int wm = (wave >> 1) * 64, wn = (wave & 1) * (BN / 2);

  f32x4 acc[4][NT];
#pragma unroll
  for (int i = 0; i < 4; i++)
#pragma unroll
    for (int j = 0; j < NT; j++) acc[i][j] = (f32x4){0.f, 0.f, 0.f, 0.f};

  for (int k0 = 0; k0 < 1024; k0 += 32) {
#pragma unroll
    for (int jj = 0; jj < 4; jj++) {
      const int call = wave * 4 + jj;
      const int c = call * 64 + lane;               // chunk id
      const int r = (c >> 2) & 127, ch = c & 3;     // row / 16B-chunk in row
      const ush* src = ((c >> 9) ? Al_g : Ah_g)
                     + (size_t)(m0 + r) * 1024 + k0 + ch * 8;
      load_lds16(src, &As[0][0][0] + (size_t)call * 512);  // 512 ush = 1KB
    }
#pragma unroll
    for (int jj = 0; jj < NT; jj++) {
      const int call = wave * NT + jj;
      const int c = call * 64 + lane;
      const int r = (c >> 2) & (BN - 1), ch = c & 3;
      const ush* src = ((c >= BN * 4) ? Bl_g : Bh_g)
                     + (size_t)(n0 + r) * 1024 + k0 + ch * 8;
      load_lds16(src, &Bs[0][0][0] + (size_t)call * 512);
    }
    __syncthreads();   // drains vmcnt -> staged data visible

    frag16 a_h[4], a_l[4], b_h[NT], b_l[NT];
#pragma unroll
    for (int s = 0; s < 4; s++) {
      const int row = wm + s * 16 + l15;
      a_h[s] = *(const frag16*)&As[0][row][quad * 8];
      a_l[s] = *(const frag16*)&As[1][row][quad * 8];
    }
#pragma unroll
    for (int t = 0; t < NT; t++) {
      const int col = wn + t * 16 + l15;
      b_h[t] = *(const frag16*)&Bs[0][col][quad * 8];
      b_l[t] = *(const frag16*)&Bs[1][col][quad * 8];
    }
#pragma unroll
    for (int mi = 0; mi < 4; mi++)
#pragma unroll
      for (int ni = 0; ni < NT; ni++) {
        acc[mi][ni] = __builtin_amdgcn_mfma_f32_16x16x32_bf16(
            a_h[mi], b_h[ni], acc[mi][ni], 0, 0, 0);
        acc[mi][ni] = __builtin_amdgcn_mfma_f32_16x16x32_bf16(
            a_h[mi], b_l[ni], acc[mi][ni], 0, 0, 0);
        acc[mi][ni] = __builtin_amdgcn_mfma_f32_16x16x32_bf16(
            a_l[mi], b_h[ni], acc[mi][ni], 0, 0, 0);
      }
    __syncthreads();
  }

#pragma unroll
  for (int mi = 0; mi < 4; mi++) {
    const int rbase = m0 + wm + mi * 16 + quad * 4;
#pragma unroll
    for (int ni = 0; ni < NT; ni++) {
      const int col = n0 + wn + ni * 16 + l15;
      const float bv = bias[col];
      const int hidx = col >> 6, d = col & 63;
#pragma unroll
      for (int r = 0; r < 4; r++) {
        const int m = rbase + r;
        float val = acc[mi][ni][r] + bv;
        if (EP == 2) {
          outf[(size_t)m * 1024 + col] = val + resid[(size_t)m * 1024 + col];
        } else {
          const int bb = m >> 10, ss = m & 1023;
          const size_t o = ((size_t)(bb * NH_ + hidx) * S_ + ss) * D_ + d;
          if (EP == 0) {
            ush hh, ll;
            split2(val, hh, ll);
            ohp[o] = hh;
            olp[o] = ll;
          } else {
            ohp[o] = bf16_rne(val);
          }
        }
      }
    }
  }
}

// ---------------------------------------------------------------------------
// V transpose: vbf [bh][s][d] bf16 -> vT [bh][d][s] bf16. (verified R10)
// ---------------------------------------------------------------------------
__global__ __launch_bounds__(256) void transpose_v(
    const ush* __restrict__ vbf, ush* __restrict__ vT) {
  __shared__ __align__(16) ush Ls[64][72];
  const int tid = threadIdx.x;
  const int s0 = blockIdx.x * 64, bh = blockIdx.y;
#pragma unroll
  for (int it = 0; it < 2; it++) {
    int flat = tid + 256 * it;
    int row = flat >> 3, dc = (flat & 7) * 8;
    *(uint4*)&Ls[row][dc] =
        *(const uint4*)&vbf[((size_t)bh * S_ + s0 + row) * D_ + dc];
  }
  __syncthreads();
#pragma unroll
  for (int it = 0; it < 2; it++) {
    int flat = tid + 256 * it;
    int drow = flat >> 3, sc = (flat & 7) * 8;
    ush v8[8];
#pragma unroll
    for (int u = 0; u < 8; u++) v8[u] = Ls[sc + u][drow];
    uint4 p;
    p.x = v8[0] | ((unsigned)v8[1] << 16); p.y = v8[2] | ((unsigned)v8[3] << 16);
    p.z = v8[4] | ((unsigned)v8[5] << 16); p.w = v8[6] | ((unsigned)v8[7] << 16);
    *(uint4*)&vT[((size_t)bh * D_ + drow) * S_ + s0 + sc] = p;
  }
}

// ---------------------------------------------------------------------------
// MFMA flash attention, staged (78us R1 structure, reverted from R2's
// direct-global experiment which was latency-bound: MfmaUtil 7%) + WINDOW:
// the reference scores include -0.1*|i-j| BEFORE softmax, so a j-tile at
// distance >192 carries relative softmax mass < e^(-19+3) ~ 1e-7 -- far
// below bf16 resolution and the 0.05 absmax budget. Process only tiles
// with |j0-q0| <= 192 (<=7 of 16 tiles; 100/256 globally = 39% of work).
// Fixed-max softmax (M=20, shift-invariant exact), far-tile path in exp2
// domain. LDS 36,864 B -> 4 blocks/CU.
// ---------------------------------------------------------------------------
__global__ __launch_bounds__(256) void attn2(
    const ush* __restrict__ qh, const ush* __restrict__ ql,
    const ush* __restrict__ kh, const ush* __restrict__ kl,
    const ush* __restrict__ vT,
    ush* __restrict__ ch, ush* __restrict__ cl) {
  __shared__ __align__(16) ush Kh[64][72], Kl[64][72];
  __shared__ __align__(16) ush VTs[64][72];   // [d][j]
  __shared__ __align__(16) ush Pst[64][72];   // [m][j]
  const int tid = threadIdx.x;
  const int lane = tid & 63, wave = tid >> 6;
  const int l15 = lane & 15, quad = lane >> 4;
  const int w16 = wave * 16;
  const int bh = blockIdx.y;
  const int b = bh >> 4, h = bh & 15;
  const int q0 = blockIdx.x * 64;

  // ---- Q fragments straight from global (A-layout: m=l15, k=quad*8+j) ----
  const size_t qrow = ((size_t)bh * S_ + q0 + w16 + l15) * D_;
  frag16 a_h[2], a_l[2];
  a_h[0] = *(const frag16*)&qh[qrow + quad * 8];
  a_h[1] = *(const frag16*)&qh[qrow + 32 + quad * 8];
  a_l[0] = *(const frag16*)&ql[qrow + quad * 8];
  a_l[1] = *(const frag16*)&ql[qrow + 32 + quad * 8];

  f32x4 o[4];
  float lrow[4];
#pragma unroll
  for (int i = 0; i < 4; i++) {
    o[i] = (f32x4){0.f, 0.f, 0.f, 0.f};
    lrow[i] = 0.f;
  }

  // exp2-domain constants: exp(x) = exp2(x*log2e)
  const float K1 = 0.18033688011112042f;   // 0.125 * log2(e)
  const float K2 = 0.14426950408889634f;   // 0.1   * log2(e)
  // far-tile: pb = exp(-0.5) constant -> fold (pb*0.125 - 20)*log2e
  const float CF = -28.853900817779268f + 0.60653066f * K1;

  const size_t kbase = (size_t)bh * S_ * D_;
  const size_t vbase = (size_t)bh * D_ * S_;

  // window: |j0 - q0| <= 192 (tile granularity; excluded mass < 1e-6 rel)
  const int jlo = (q0 > 192) ? q0 - 192 : 0;
  const int jend = (q0 + 256 < S_) ? q0 + 256 : S_;

  for (int j0 = jlo; j0 < jend; j0 += 64) {
    __syncthreads();   // prior tile's frag reads done
#pragma unroll
    for (int it = 0; it < 2; it++) {
      const int flat = tid + 256 * it;
      const int row = flat >> 3, dc = (flat & 7) * 8;
      const size_t gk = kbase + (size_t)(j0 + row) * D_ + dc;
      *(uint4*)&Kh[row][dc] = *(const uint4*)&kh[gk];
      *(uint4*)&Kl[row][dc] = *(const uint4*)&kl[gk];
      *(uint4*)&VTs[row][dc] =
          *(const uint4*)&vT[vbase + (size_t)row * S_ + j0 + dc];
    }
    __syncthreads();

    // ---- S = Q.K^T (3-term split) ----
    f32x4 c4[4];
#pragma unroll
    for (int nt = 0; nt < 4; nt++) c4[nt] = (f32x4){0.f, 0.f, 0.f, 0.f};
#pragma unroll
    for (int kk = 0; kk < 2; kk++) {
#pragma unroll
      for (int nt = 0; nt < 4; nt++) {
        frag16 bh_ = *(const frag16*)&Kh[nt * 16 + l15][kk * 32 + quad * 8];
        frag16 bl_ = *(const frag16*)&Kl[nt * 16 + l15][kk * 32 + quad * 8];
        c4[nt] = __builtin_amdgcn_mfma_f32_16x16x32_bf16(a_h[kk], bh_, c4[nt], 0, 0, 0);
        c4[nt] = __builtin_amdgcn_mfma_f32_16x16x32_bf16(a_l[kk], bh_, c4[nt], 0, 0, 0);
        c4[nt] = __builtin_amdgcn_mfma_f32_16x16x32_bf16(a_h[kk], bl_, c4[nt], 0, 0, 0);
      }
    }

    // ---- bias + fixed-max exp + P store (C-layout: row=quad*4+r) ----
    const bool far = (j0 >= q0 + 68) || (q0 >= j0 + 68);
    const float fb = (float)(q0 + w16 + quad * 4 - j0 - l15);
#pragma unroll
    for (int r = 0; r < 4; r++) {
#pragma unroll
      for (int nt = 0; nt < 4; nt++) {
        const float df = fb + (float)r - 16.0f * (float)nt;   // qi - jj
        const float dist = fabsf(df);
        float sv;
        if (far) {
          sv = exp2f(fmaf(c4[nt][r], K1, fmaf(dist, -K2, CF)));
        } else {
          const float pb = __expf(-0.1f * fminf(dist, 5.0f));
          sv = __expf((c4[nt][r] + pb) * 0.125f - 0.1f * dist - 20.0f);
        }
        lrow[r] += sv;
        Pst[w16 + quad * 4 + r][nt * 16 + l15] = bf16_rne(sv);
      }
    }

    // ---- PV (own rows only; same-wave LDS ordering, no barrier) ----
    frag16 pa[2];
    pa[0] = *(const frag16*)&Pst[w16 + l15][quad * 8];
    pa[1] = *(const frag16*)&Pst[w16 + l15][32 + quad * 8];
#pragma unroll
    for (int dt = 0; dt < 4; dt++) {
      frag16 vb0 = *(const frag16*)&VTs[dt * 16 + l15][quad * 8];
      frag16 vb1 = *(const frag16*)&VTs[dt * 16 + l15][32 + quad * 8];
      o[dt] = __builtin_amdgcn_mfma_f32_16x16x32_bf16(pa[0], vb0, o[dt], 0, 0, 0);
      o[dt] = __builtin_amdgcn_mfma_f32_16x16x32_bf16(pa[1], vb1, o[dt], 0, 0, 0);
    }
  }

  // ---- deferred row-sum reduction + normalize + write pre-split ctx ----
#pragma unroll
  for (int r = 0; r < 4; r++) {
#pragma unroll
    for (int off = 1; off < 16; off <<= 1) lrow[r] += __shfl_xor(lrow[r], off);
    const float inv = 1.0f / lrow[r];
    const size_t rowp =
        ((size_t)(b * S_ + q0 + w16 + quad * 4 + r)) * H_ + h * 64;
#pragma unroll
    for (int dt = 0; dt < 4; dt++) {
      ush hh, ll;
      split2(o[dt][r] * inv, hh, ll);
      ch[rowp + dt * 16 + l15] = hh;
      cl[rowp + dt * 16 + l15] = ll;
    }
  }
}

// ---------------------------------------------------------------------------
// Fused LayerNorm + span logits: one block per row. (verified R10)
// ---------------------------------------------------------------------------
__global__ __launch_bounds__(256) void ln_span(
    const float* __restrict__ y, const float* __restrict__ g,
    const float* __restrict__ bta, const float* __restrict__ Wsp,
    const float* __restrict__ bs, float* __restrict__ logits) {
  const int row = blockIdx.x;
  const int tid = threadIdx.x, lane = tid & 63, wave = tid >> 6;
  const float* yr = y + (size_t)row * 1024;
  float vals[4], s = 0.f, s2 = 0.f;
#pragma unroll
  for (int i = 0; i < 4; i++) {
    float t = yr[tid + i * 256];
    vals[i] = t; s += t; s2 += t * t;
  }
#pragma unroll
  for (int off = 32; off; off >>= 1) {
    s += __shfl_xor(s, off);
    s2 += __shfl_xor(s2, off);
  }
  __shared__ float red[8];
  __shared__ float red9[4][12];
  if (lane == 0) { red[wave] = s; red[4 + wave] = s2; }
  __syncthreads();
  s = red[0] + red[1] + red[2] + red[3];
  s2 = red[4] + red[5] + red[6] + red[7];
  const float mu = s * (1.0f / 1024.0f);
  const float var = s2 * (1.0f / 1024.0f) - mu * mu;
  const float inv = rsqrtf(var + 1e-5f);

  float lg[9];
#pragma unroll
  for (int l = 0; l < 9; l++) lg[l] = 0.f;
#pragma unroll
  for (int i = 0; i < 4; i++) {
    const int hh = tid + i * 256;
    const float yn = (vals[i] - mu) * inv * g[hh] + bta[hh];
#pragma unroll
    for (int l = 0; l < 9; l++) lg[l] += yn * Wsp[hh * 9 + l];
  }
#pragma unroll
  for (int l = 0; l < 9; l++) {
#pragma unroll
    for (int off = 32; off; off >>= 1) lg[l] += __shfl_xor(lg[l], off);
  }
  if (lane == 0) {
#pragma unroll
    for (int l = 0; l < 9; l++) red9[wave][l] = lg[l];
  }
  __syncthreads();
  if (tid < 9) {
    logits[(size_t)row * 9 + tid] =
        red9[0][tid] + red9[1][tid] + red9[2][tid] + red9[3][tid] + bs[tid];
  }
}

// ---------------------------------------------------------------------------
// Entity-bias adjustment + FP32 output. One thread per token.
// ---------------------------------------------------------------------------
__global__ __launch_bounds__(256) void final_kernel(
    const float* __restrict__ logits, const float* __restrict__ eb,
    float* __restrict__ out) {
  const int m = blockIdx.x * 256 + threadIdx.x;
  const int i = m & 1023;
  float cur[9];
#pragma unroll
  for (int l = 0; l < 9; l++) cur[l] = logits[(size_t)m * 9 + l];
  if (i > 0) {
    const float* prev = logits + (size_t)(m - 1) * 9;
    int am = 0;
    float best = prev[0];
#pragma unroll
    for (int l = 1; l < 9; l++) {
      float pv = prev[l];
      if (pv > best) { best = pv; am = l; }
    }
    if (am == 1) cur[2] += 2.0f * eb[2];
  }
#pragma unroll
  for (int l = 0; l < 9; l++) out[(size_t)m * 9 + l] = cur[l];
}

// ---------------------------------------------------------------------------
extern "C" void kernel_launch(void* const* d_in, const int* in_sizes, int n_in,
                              void* d_out, int out_size, void* d_ws, size_t ws_size,
                              hipStream_t stream) {
  const float* x    = (const float*)d_in[0];
  const float* Wq   = (const float*)d_in[1];
  const float* bq   = (const float*)d_in[2];
  const float* Wk   = (const float*)d_in[3];
  const float* bk   = (const float*)d_in[4];
  const float* Wv   = (const float*)d_in[5];
  const float* bv   = (const float*)d_in[6];
  const float* Wo   = (const float*)d_in[7];
  const float* bo   = (const float*)d_in[8];
  const float* ln_g = (const float*)d_in[9];
  const float* ln_b = (const float*)d_in[10];
  const float* Ws   = (const float*)d_in[11];
  const float* bs   = (const float*)d_in[12];
  const float* eb   = (const float*)d_in[13];
  float* out = (float*)d_out;
  char* W8 = (char*)d_ws;

  // ---- ws layout, 64 MB envelope with phase-aliasing ----
  ush* WoT_h = (ush*)(W8 + 0 * MB_);
  ush* WoT_l = (ush*)(W8 + 2 * MB_);
  ush* WqT_h = (ush*)(W8 + 4 * MB_);
  ush* WqT_l = (ush*)(W8 + 6 * MB_);
  ush* WkT_h = (ush*)(W8 + 8 * MB_);
  ush* WkT_l = (ush*)(W8 + 10 * MB_);
  ush* WvT_h = (ush*)(W8 + 12 * MB_);
  ush* WvT_l = (ush*)(W8 + 14 * MB_);
  ush* xh    = (ush*)(W8 + 16 * MB_);
  ush* xl    = (ush*)(W8 + 24 * MB_);
  ush* qh    = (ush*)(W8 + 32 * MB_);
  ush* ql    = (ush*)(W8 + 40 * MB_);
  ush* kh    = (ush*)(W8 + 48 * MB_);
  ush* kl    = (ush*)(W8 + 56 * MB_);
  // aliases:
  ush*   vbf  = (ush*)(W8 + 4 * MB_);    // over WqT+WkT (dead after qk dispatch), 8 MB
  ush*   vT   = (ush*)(W8 + 16 * MB_);   // over xh (dead after v-gemm)
  ush*   ctxh = (ush*)(W8 + 24 * MB_);   // over xl (dead)
  ush*   ctxl = (ush*)(W8 + 4 * MB_);    // over vbf (dead after transpose)
  float* y_ws = (float*)(W8 + 32 * MB_); // over qh/ql (dead after attn)
  float* lg_ws = (float*)(W8 + 48 * MB_);// over kh (dead after attn)

  split_wT4<<<dim3(16, 16, 4), 256, 0, stream>>>(
      Wq, Wk, Wv, Wo, WqT_h, WqT_l, WkT_h, WkT_l, WvT_h, WvT_l, WoT_h, WoT_l);
  split_x<<<2048, 256, 0, stream>>>(x, xh, xl);

  // Q+K fused: z selects {Wq->qh/ql, Wk->kh/kl}. 512 blocks = 2/CU.
  gemm_big<0, 128><<<dim3(8, 32, 2), 256, 0, stream>>>(
      xh, xl, WqT_h, WqT_l, WkT_h, WkT_l, bq, bk,
      nullptr, nullptr, qh, ql, kh, kl);
  // V (after qk so vbf can alias dead WqT/WkT). 512 blocks = 2/CU.
  gemm_big<1, 64><<<dim3(16, 32), 256, 0, stream>>>(
      xh, xl, WvT_h, WvT_l, nullptr, nullptr, bv, nullptr,
      nullptr, nullptr, vbf, nullptr, nullptr, nullptr);
  transpose_v<<<dim3(16, 64), 256, 0, stream>>>(vbf, vT);
  attn2<<<dim3(16, 64), 256, 0, stream>>>(qh, ql, kh, kl, vT, ctxh, ctxl);
  // O-proj + residual. 512 blocks = 2/CU.
  gemm_big<2, 64><<<dim3(16, 32), 256, 0, stream>>>(
      ctxh, ctxl, WoT_h, WoT_l, nullptr, nullptr, bo, nullptr,
      x, y_ws, nullptr, nullptr, nullptr, nullptr);
  ln_span<<<4096, 256, 0, stream>>>(y_ws, ln_g, ln_b, Ws, bs, lg_ws);
  final_kernel<<<16, 256, 0, stream>>>(lg_ws, eb, out);
}

// Round 4
// 292.192 us; speedup vs baseline: 1.4628x; 1.0276x over previous
//
#include <hip/hip_runtime.h>
#include <hip/hip_bf16.h>
#include <math.h>

typedef unsigned short ush;
typedef __attribute__((ext_vector_type(8))) short frag16;   // 8 bf16 = 4 VGPRs
typedef __attribute__((ext_vector_type(4))) float f32x4;

#define S_   1024
#define H_   1024
#define NH_  16
#define D_   64
#define L_   9
#define MB_  (1048576ull)

__device__ __forceinline__ ush bf16_rne(float x) {
  unsigned int b = __float_as_uint(x);
  b += 0x7FFFu + ((b >> 16) & 1u);
  return (ush)(b >> 16);
}
__device__ __forceinline__ void split2(float x, ush& h, ush& l) {
  h = bf16_rne(x);
  l = bf16_rne(x - __uint_as_float((unsigned int)h << 16));
}

// async global->LDS, 16B per lane; lds ptr must be wave-uniform base.
__device__ __forceinline__ void load_lds16(const ush* g, const ush* l) {
  __builtin_amdgcn_global_load_lds(
      (const __attribute__((address_space(1))) void*)g,
      (__attribute__((address_space(3))) void*)l, 16, 0, 0);
}

// ---------------------------------------------------------------------------
// Split + transpose 4 weights in one launch. W [k][n] fp32 -> WTh/WTl [n][k]
// bf16. Grid (16,16,4). (verified R10)
// ---------------------------------------------------------------------------
__global__ __launch_bounds__(256) void split_wT4(
    const float* W0, const float* W1, const float* W2, const float* W3,
    ush* h0, ush* l0, ush* h1, ush* l1, ush* h2, ush* l2, ush* h3, ush* l3) {
  __shared__ __align__(16) float Ls[64][68];
  const float* W = (blockIdx.z == 0) ? W0 : (blockIdx.z == 1) ? W1
                 : (blockIdx.z == 2) ? W2 : W3;
  ush* Th = (blockIdx.z == 0) ? h0 : (blockIdx.z == 1) ? h1
          : (blockIdx.z == 2) ? h2 : h3;
  ush* Tl = (blockIdx.z == 0) ? l0 : (blockIdx.z == 1) ? l1
          : (blockIdx.z == 2) ? l2 : l3;
  const int tid = threadIdx.x;
  const int n0 = blockIdx.x * 64, k0 = blockIdx.y * 64;
#pragma unroll
  for (int it = 0; it < 4; it++) {
    int flat = tid + 256 * it;
    int row = flat >> 4, nc = (flat & 15) * 4;
    *(float4*)&Ls[row][nc] = *(const float4*)&W[(size_t)(k0 + row) * 1024 + n0 + nc];
  }
  __syncthreads();
#pragma unroll
  for (int it = 0; it < 2; it++) {
    int flat = tid + 256 * it;
    int nrow = flat >> 3, kc = (flat & 7) * 8;
    ush hs[8], ls[8];
#pragma unroll
    for (int u = 0; u < 8; u++) split2(Ls[kc + u][nrow], hs[u], ls[u]);
    uint4 ph, pl;
    ph.x = hs[0] | ((unsigned)hs[1] << 16); ph.y = hs[2] | ((unsigned)hs[3] << 16);
    ph.z = hs[4] | ((unsigned)hs[5] << 16); ph.w = hs[6] | ((unsigned)hs[7] << 16);
    pl.x = ls[0] | ((unsigned)ls[1] << 16); pl.y = ls[2] | ((unsigned)ls[3] << 16);
    pl.z = ls[4] | ((unsigned)ls[5] << 16); pl.w = ls[6] | ((unsigned)ls[7] << 16);
    size_t o = (size_t)(n0 + nrow) * 1024 + k0 + kc;
    *(uint4*)&Th[o] = ph;
    *(uint4*)&Tl[o] = pl;
  }
}

// ---------------------------------------------------------------------------
// Pre-split x: fp32 [4096x1024] -> xh, xl bf16 row-major. Grid 2048.
// ---------------------------------------------------------------------------
__global__ __launch_bounds__(256) void split_x(
    const float* __restrict__ x, ush* __restrict__ xh, ush* __restrict__ xl) {
  const size_t i = ((size_t)blockIdx.x * 256 + threadIdx.x) * 8;
  float4 a = *(const float4*)&x[i];
  float4 b = *(const float4*)&x[i + 4];
  const float v[8] = {a.x, a.y, a.z, a.w, b.x, b.y, b.z, b.w};
  ush h[8], l[8];
#pragma unroll
  for (int u = 0; u < 8; u++) split2(v[u], h[u], l[u]);
  uint4 ph, pl;
  ph.x = h[0] | ((unsigned)h[1] << 16); ph.y = h[2] | ((unsigned)h[3] << 16);
  ph.z = h[4] | ((unsigned)h[5] << 16); ph.w = h[6] | ((unsigned)h[7] << 16);
  pl.x = l[0] | ((unsigned)l[1] << 16); pl.y = l[2] | ((unsigned)l[3] << 16);
  pl.z = l[4] | ((unsigned)l[5] << 16); pl.w = l[6] | ((unsigned)l[7] << 16);
  *(uint4*)&xh[i] = ph;
  *(uint4*)&xl[i] = pl;
}

// ---------------------------------------------------------------------------
// m97-structure split-bf16 GEMM + DOUBLE-BUFFERED PREFETCH (T3 minimum
// 2-phase): stage K-step t+1 via global_load_lds BEFORE computing t; one
// __syncthreads per K-step (drains vmcnt -> t+1 staged; protects WAR on
// the buffer overwritten at t+2). LDS 64KB (BN=128) / 48KB (BN=64) --
// free, occupancy is grid-limited at 2 blocks/CU.
// EP: 0 = split bf16 out to head layout, z in {0,1} selects q/k set;
//     1 = bf16 out to head layout (v);
//     2 = fp32 [m][n] + bias + residual (o-proj).
// ---------------------------------------------------------------------------
template <int EP, int BN>
__global__ __launch_bounds__(256) void gemm_big(
    const ush* __restrict__ Ah_g, const ush* __restrict__ Al_g,
    const ush* __restrict__ Bh0, const ush* __restrict__ Bl0,
    const ush* __restrict__ Bh1, const ush* __restrict__ Bl1,
    const float* __restrict__ bias0, const float* __restrict__ bias1,
    const float* __restrict__ resid, float* __restrict__ outf,
    ush* __restrict__ o0h, ush* __restrict__ o0l,
    ush* __restrict__ o1h, ush* __restrict__ o1l) {
  constexpr int NT = BN / 32;                    // frag cols per wave
  __shared__ __align__(16) ush As[2][2][128][32];  // [buf][hl][m][k]
  __shared__ __align__(16) ush Bs[2][2][BN][32];   // [buf][hl][n][k]
  const int tid = threadIdx.x, lane = tid & 63, wave = tid >> 6;
  const int l15 = lane & 15, quad = lane >> 4;
  const int m0 = blockIdx.y * 128, n0 = blockIdx.x * BN;

  const int z = (EP == 0) ? blockIdx.z : 0;
  const ush* Bh_g = z ? Bh1 : Bh0;
  const ush* Bl_g = z ? Bl1 : Bl0;
  const float* bias = z ? bias1 : bias0;
  ush* ohp = z ? o1h : o0h;
  ush* olp = z ? o1l : o0l;

  const int wm = (wave >> 1) * 64, wn = (wave & 1) * (BN / 2);

  f32x4 acc[4][NT];
#pragma unroll
  for (int i = 0; i < 4; i++)
#pragma unroll
    for (int j = 0; j < NT; j++) acc[i][j] = (f32x4){0.f, 0.f, 0.f, 0.f};

  // stage one BK=32 K-slab into buffer bi (async, copy-only)
  auto stage = [&](int bi, int k0) {
#pragma unroll
    for (int jj = 0; jj < 4; jj++) {
      const int call = wave * 4 + jj;
      const int c = call * 64 + lane;               // chunk id
      const int r = (c >> 2) & 127, ch = c & 3;     // row / 16B-chunk in row
      const ush* src = ((c >> 9) ? Al_g : Ah_g)
                     + (size_t)(m0 + r) * 1024 + k0 + ch * 8;
      load_lds16(src, &As[bi][0][0][0] + (size_t)call * 512);  // 1KB/call
    }
#pragma unroll
    for (int jj = 0; jj < NT; jj++) {
      const int call = wave * NT + jj;
      const int c = call * 64 + lane;
      const int r = (c >> 2) & (BN - 1), ch = c & 3;
      const ush* src = ((c >= BN * 4) ? Bl_g : Bh_g)
                     + (size_t)(n0 + r) * 1024 + k0 + ch * 8;
      load_lds16(src, &Bs[bi][0][0][0] + (size_t)call * 512);
    }
  };

  stage(0, 0);
  __syncthreads();   // buf0 staged

  for (int k0 = 0; k0 < 1024; k0 += 32) {
    const int cur = (k0 >> 5) & 1;
    if (k0 + 32 < 1024) stage(cur ^ 1, k0 + 32);   // prefetch, in flight

    frag16 a_h[4], a_l[4], b_h[NT], b_l[NT];
#pragma unroll
    for (int s = 0; s < 4; s++) {
      const int row = wm + s * 16 + l15;
      a_h[s] = *(const frag16*)&As[cur][0][row][quad * 8];
      a_l[s] = *(const frag16*)&As[cur][1][row][quad * 8];
    }
#pragma unroll
    for (int t = 0; t < NT; t++) {
      const int col = wn + t * 16 + l15;
      b_h[t] = *(const frag16*)&Bs[cur][0][col][quad * 8];
      b_l[t] = *(const frag16*)&Bs[cur][1][col][quad * 8];
    }
#pragma unroll
    for (int mi = 0; mi < 4; mi++)
#pragma unroll
      for (int ni = 0; ni < NT; ni++) {
        acc[mi][ni] = __builtin_amdgcn_mfma_f32_16x16x32_bf16(
            a_h[mi], b_h[ni], acc[mi][ni], 0, 0, 0);
        acc[mi][ni] = __builtin_amdgcn_mfma_f32_16x16x32_bf16(
            a_h[mi], b_l[ni], acc[mi][ni], 0, 0, 0);
        acc[mi][ni] = __builtin_amdgcn_mfma_f32_16x16x32_bf16(
            a_l[mi], b_h[ni], acc[mi][ni], 0, 0, 0);
      }
    __syncthreads();   // drains prefetch; all reads of cur done before reuse
  }

#pragma unroll
  for (int mi = 0; mi < 4; mi++) {
    const int rbase = m0 + wm + mi * 16 + quad * 4;
#pragma unroll
    for (int ni = 0; ni < NT; ni++) {
      const int col = n0 + wn + ni * 16 + l15;
      const float bv = bias[col];
      const int hidx = col >> 6, d = col & 63;
#pragma unroll
      for (int r = 0; r < 4; r++) {
        const int m = rbase + r;
        float val = acc[mi][ni][r] + bv;
        if (EP == 2) {
          outf[(size_t)m * 1024 + col] = val + resid[(size_t)m * 1024 + col];
        } else {
          const int bb = m >> 10, ss = m & 1023;
          const size_t o = ((size_t)(bb * NH_ + hidx) * S_ + ss) * D_ + d;
          if (EP == 0) {
            ush hh, ll;
            split2(val, hh, ll);
            ohp[o] = hh;
            olp[o] = ll;
          } else {
            ohp[o] = bf16_rne(val);
          }
        }
      }
    }
  }
}

// ---------------------------------------------------------------------------
// V transpose: vbf [bh][s][d] bf16 -> vT [bh][d][s] bf16. (verified R10)
// ---------------------------------------------------------------------------
__global__ __launch_bounds__(256) void transpose_v(
    const ush* __restrict__ vbf, ush* __restrict__ vT) {
  __shared__ __align__(16) ush Ls[64][72];
  const int tid = threadIdx.x;
  const int s0 = blockIdx.x * 64, bh = blockIdx.y;
#pragma unroll
  for (int it = 0; it < 2; it++) {
    int flat = tid + 256 * it;
    int row = flat >> 3, dc = (flat & 7) * 8;
    *(uint4*)&Ls[row][dc] =
        *(const uint4*)&vbf[((size_t)bh * S_ + s0 + row) * D_ + dc];
  }
  __syncthreads();
#pragma unroll
  for (int it = 0; it < 2; it++) {
    int flat = tid + 256 * it;
    int drow = flat >> 3, sc = (flat & 7) * 8;
    ush v8[8];
#pragma unroll
    for (int u = 0; u < 8; u++) v8[u] = Ls[sc + u][drow];
    uint4 p;
    p.x = v8[0] | ((unsigned)v8[1] << 16); p.y = v8[2] | ((unsigned)v8[3] << 16);
    p.z = v8[4] | ((unsigned)v8[5] << 16); p.w = v8[6] | ((unsigned)v8[7] << 16);
    *(uint4*)&vT[((size_t)bh * D_ + drow) * S_ + s0 + sc] = p;
  }
}

// ---------------------------------------------------------------------------
// MFMA flash attention, staged + window |j0-q0| <= 192 (verified R3:
// excluded softmax mass < 2e-6 relative, absmax bit-identical).
// Fixed-max softmax (M=20, shift-invariant exact), far-tile path in exp2
// domain. LDS 36,864 B -> 4 blocks/CU.
// ---------------------------------------------------------------------------
__global__ __launch_bounds__(256) void attn2(
    const ush* __restrict__ qh, const ush* __restrict__ ql,
    const ush* __restrict__ kh, const ush* __restrict__ kl,
    const ush* __restrict__ vT,
    ush* __restrict__ ch, ush* __restrict__ cl) {
  __shared__ __align__(16) ush Kh[64][72], Kl[64][72];
  __shared__ __align__(16) ush VTs[64][72];   // [d][j]
  __shared__ __align__(16) ush Pst[64][72];   // [m][j]
  const int tid = threadIdx.x;
  const int lane = tid & 63, wave = tid >> 6;
  const int l15 = lane & 15, quad = lane >> 4;
  const int w16 = wave * 16;
  const int bh = blockIdx.y;
  const int b = bh >> 4, h = bh & 15;
  const int q0 = blockIdx.x * 64;

  // ---- Q fragments straight from global (A-layout: m=l15, k=quad*8+j) ----
  const size_t qrow = ((size_t)bh * S_ + q0 + w16 + l15) * D_;
  frag16 a_h[2], a_l[2];
  a_h[0] = *(const frag16*)&qh[qrow + quad * 8];
  a_h[1] = *(const frag16*)&qh[qrow + 32 + quad * 8];
  a_l[0] = *(const frag16*)&ql[qrow + quad * 8];
  a_l[1] = *(const frag16*)&ql[qrow + 32 + quad * 8];

  f32x4 o[4];
  float lrow[4];
#pragma unroll
  for (int i = 0; i < 4; i++) {
    o[i] = (f32x4){0.f, 0.f, 0.f, 0.f};
    lrow[i] = 0.f;
  }

  // exp2-domain constants: exp(x) = exp2(x*log2e)
  const float K1 = 0.18033688011112042f;   // 0.125 * log2(e)
  const float K2 = 0.14426950408889634f;   // 0.1   * log2(e)
  // far-tile: pb = exp(-0.5) constant -> fold (pb*0.125 - 20)*log2e
  const float CF = -28.853900817779268f + 0.60653066f * K1;

  const size_t kbase = (size_t)bh * S_ * D_;
  const size_t vbase = (size_t)bh * D_ * S_;

  // window: |j0 - q0| <= 192 (tile granularity; excluded mass < 1e-6 rel)
  const int jlo = (q0 > 192) ? q0 - 192 : 0;
  const int jend = (q0 + 256 < S_) ? q0 + 256 : S_;

  for (int j0 = jlo; j0 < jend; j0 += 64) {
    __syncthreads();   // prior tile's frag reads done
#pragma unroll
    for (int it = 0; it < 2; it++) {
      const int flat = tid + 256 * it;
      const int row = flat >> 3, dc = (flat & 7) * 8;
      const size_t gk = kbase + (size_t)(j0 + row) * D_ + dc;
      *(uint4*)&Kh[row][dc] = *(const uint4*)&kh[gk];
      *(uint4*)&Kl[row][dc] = *(const uint4*)&kl[gk];
      *(uint4*)&VTs[row][dc] =
          *(const uint4*)&vT[vbase + (size_t)row * S_ + j0 + dc];
    }
    __syncthreads();

    // ---- S = Q.K^T (3-term split) ----
    f32x4 c4[4];
#pragma unroll
    for (int nt = 0; nt < 4; nt++) c4[nt] = (f32x4){0.f, 0.f, 0.f, 0.f};
#pragma unroll
    for (int kk = 0; kk < 2; kk++) {
#pragma unroll
      for (int nt = 0; nt < 4; nt++) {
        frag16 bh_ = *(const frag16*)&Kh[nt * 16 + l15][kk * 32 + quad * 8];
        frag16 bl_ = *(const frag16*)&Kl[nt * 16 + l15][kk * 32 + quad * 8];
        c4[nt] = __builtin_amdgcn_mfma_f32_16x16x32_bf16(a_h[kk], bh_, c4[nt], 0, 0, 0);
        c4[nt] = __builtin_amdgcn_mfma_f32_16x16x32_bf16(a_l[kk], bh_, c4[nt], 0, 0, 0);
        c4[nt] = __builtin_amdgcn_mfma_f32_16x16x32_bf16(a_h[kk], bl_, c4[nt], 0, 0, 0);
      }
    }

    // ---- bias + fixed-max exp + P store (C-layout: row=quad*4+r) ----
    const bool far = (j0 >= q0 + 68) || (q0 >= j0 + 68);
    const float fb = (float)(q0 + w16 + quad * 4 - j0 - l15);
#pragma unroll
    for (int r = 0; r < 4; r++) {
#pragma unroll
      for (int nt = 0; nt < 4; nt++) {
        const float df = fb + (float)r - 16.0f * (float)nt;   // qi - jj
        const float dist = fabsf(df);
        float sv;
        if (far) {
          sv = exp2f(fmaf(c4[nt][r], K1, fmaf(dist, -K2, CF)));
        } else {
          const float pb = __expf(-0.1f * fminf(dist, 5.0f));
          sv = __expf((c4[nt][r] + pb) * 0.125f - 0.1f * dist - 20.0f);
        }
        lrow[r] += sv;
        Pst[w16 + quad * 4 + r][nt * 16 + l15] = bf16_rne(sv);
      }
    }

    // ---- PV (own rows only; same-wave LDS ordering, no barrier) ----
    frag16 pa[2];
    pa[0] = *(const frag16*)&Pst[w16 + l15][quad * 8];
    pa[1] = *(const frag16*)&Pst[w16 + l15][32 + quad * 8];
#pragma unroll
    for (int dt = 0; dt < 4; dt++) {
      frag16 vb0 = *(const frag16*)&VTs[dt * 16 + l15][quad * 8];
      frag16 vb1 = *(const frag16*)&VTs[dt * 16 + l15][32 + quad * 8];
      o[dt] = __builtin_amdgcn_mfma_f32_16x16x32_bf16(pa[0], vb0, o[dt], 0, 0, 0);
      o[dt] = __builtin_amdgcn_mfma_f32_16x16x32_bf16(pa[1], vb1, o[dt], 0, 0, 0);
    }
  }

  // ---- deferred row-sum reduction + normalize + write pre-split ctx ----
#pragma unroll
  for (int r = 0; r < 4; r++) {
#pragma unroll
    for (int off = 1; off < 16; off <<= 1) lrow[r] += __shfl_xor(lrow[r], off);
    const float inv = 1.0f / lrow[r];
    const size_t rowp =
        ((size_t)(b * S_ + q0 + w16 + quad * 4 + r)) * H_ + h * 64;
#pragma unroll
    for (int dt = 0; dt < 4; dt++) {
      ush hh, ll;
      split2(o[dt][r] * inv, hh, ll);
      ch[rowp + dt * 16 + l15] = hh;
      cl[rowp + dt * 16 + l15] = ll;
    }
  }
}

// ---------------------------------------------------------------------------
// Fused LayerNorm + span logits: one block per row. (verified R10)
// ---------------------------------------------------------------------------
__global__ __launch_bounds__(256) void ln_span(
    const float* __restrict__ y, const float* __restrict__ g,
    const float* __restrict__ bta, const float* __restrict__ Wsp,
    const float* __restrict__ bs, float* __restrict__ logits) {
  const int row = blockIdx.x;
  const int tid = threadIdx.x, lane = tid & 63, wave = tid >> 6;
  const float* yr = y + (size_t)row * 1024;
  float vals[4], s = 0.f, s2 = 0.f;
#pragma unroll
  for (int i = 0; i < 4; i++) {
    float t = yr[tid + i * 256];
    vals[i] = t; s += t; s2 += t * t;
  }
#pragma unroll
  for (int off = 32; off; off >>= 1) {
    s += __shfl_xor(s, off);
    s2 += __shfl_xor(s2, off);
  }
  __shared__ float red[8];
  __shared__ float red9[4][12];
  if (lane == 0) { red[wave] = s; red[4 + wave] = s2; }
  __syncthreads();
  s = red[0] + red[1] + red[2] + red[3];
  s2 = red[4] + red[5] + red[6] + red[7];
  const float mu = s * (1.0f / 1024.0f);
  const float var = s2 * (1.0f / 1024.0f) - mu * mu;
  const float inv = rsqrtf(var + 1e-5f);

  float lg[9];
#pragma unroll
  for (int l = 0; l < 9; l++) lg[l] = 0.f;
#pragma unroll
  for (int i = 0; i < 4; i++) {
    const int hh = tid + i * 256;
    const float yn = (vals[i] - mu) * inv * g[hh] + bta[hh];
#pragma unroll
    for (int l = 0; l < 9; l++) lg[l] += yn * Wsp[hh * 9 + l];
  }
#pragma unroll
  for (int l = 0; l < 9; l++) {
#pragma unroll
    for (int off = 32; off; off >>= 1) lg[l] += __shfl_xor(lg[l], off);
  }
  if (lane == 0) {
#pragma unroll
    for (int l = 0; l < 9; l++) red9[wave][l] = lg[l];
  }
  __syncthreads();
  if (tid < 9) {
    logits[(size_t)row * 9 + tid] =
        red9[0][tid] + red9[1][tid] + red9[2][tid] + red9[3][tid] + bs[tid];
  }
}

// ---------------------------------------------------------------------------
// Entity-bias adjustment + FP32 output. One thread per token.
// ---------------------------------------------------------------------------
__global__ __launch_bounds__(256) void final_kernel(
    const float* __restrict__ logits, const float* __restrict__ eb,
    float* __restrict__ out) {
  const int m = blockIdx.x * 256 + threadIdx.x;
  const int i = m & 1023;
  float cur[9];
#pragma unroll
  for (int l = 0; l < 9; l++) cur[l] = logits[(size_t)m * 9 + l];
  if (i > 0) {
    const float* prev = logits + (size_t)(m - 1) * 9;
    int am = 0;
    float best = prev[0];
#pragma unroll
    for (int l = 1; l < 9; l++) {
      float pv = prev[l];
      if (pv > best) { best = pv; am = l; }
    }
    if (am == 1) cur[2] += 2.0f * eb[2];
  }
#pragma unroll
  for (int l = 0; l < 9; l++) out[(size_t)m * 9 + l] = cur[l];
}

// ---------------------------------------------------------------------------
extern "C" void kernel_launch(void* const* d_in, const int* in_sizes, int n_in,
                              void* d_out, int out_size, void* d_ws, size_t ws_size,
                              hipStream_t stream) {
  const float* x    = (const float*)d_in[0];
  const float* Wq   = (const float*)d_in[1];
  const float* bq   = (const float*)d_in[2];
  const float* Wk   = (const float*)d_in[3];
  const float* bk   = (const float*)d_in[4];
  const float* Wv   = (const float*)d_in[5];
  const float* bv   = (const float*)d_in[6];
  const float* Wo   = (const float*)d_in[7];
  const float* bo   = (const float*)d_in[8];
  const float* ln_g = (const float*)d_in[9];
  const float* ln_b = (const float*)d_in[10];
  const float* Ws   = (const float*)d_in[11];
  const float* bs   = (const float*)d_in[12];
  const float* eb   = (const float*)d_in[13];
  float* out = (float*)d_out;
  char* W8 = (char*)d_ws;

  // ---- ws layout, 64 MB envelope with phase-aliasing ----
  ush* WoT_h = (ush*)(W8 + 0 * MB_);
  ush* WoT_l = (ush*)(W8 + 2 * MB_);
  ush* WqT_h = (ush*)(W8 + 4 * MB_);
  ush* WqT_l = (ush*)(W8 + 6 * MB_);
  ush* WkT_h = (ush*)(W8 + 8 * MB_);
  ush* WkT_l = (ush*)(W8 + 10 * MB_);
  ush* WvT_h = (ush*)(W8 + 12 * MB_);
  ush* WvT_l = (ush*)(W8 + 14 * MB_);
  ush* xh    = (ush*)(W8 + 16 * MB_);
  ush* xl    = (ush*)(W8 + 24 * MB_);
  ush* qh    = (ush*)(W8 + 32 * MB_);
  ush* ql    = (ush*)(W8 + 40 * MB_);
  ush* kh    = (ush*)(W8 + 48 * MB_);
  ush* kl    = (ush*)(W8 + 56 * MB_);
  // aliases:
  ush*   vbf  = (ush*)(W8 + 4 * MB_);    // over WqT+WkT (dead after qk dispatch), 8 MB
  ush*   vT   = (ush*)(W8 + 16 * MB_);   // over xh (dead after v-gemm)
  ush*   ctxh = (ush*)(W8 + 24 * MB_);   // over xl (dead)
  ush*   ctxl = (ush*)(W8 + 4 * MB_);    // over vbf (dead after transpose)
  float* y_ws = (float*)(W8 + 32 * MB_); // over qh/ql (dead after attn)
  float* lg_ws = (float*)(W8 + 48 * MB_);// over kh (dead after attn)

  split_wT4<<<dim3(16, 16, 4), 256, 0, stream>>>(
      Wq, Wk, Wv, Wo, WqT_h, WqT_l, WkT_h, WkT_l, WvT_h, WvT_l, WoT_h, WoT_l);
  split_x<<<2048, 256, 0, stream>>>(x, xh, xl);

  // Q+K fused: z selects {Wq->qh/ql, Wk->kh/kl}. 512 blocks = 2/CU.
  gemm_big<0, 128><<<dim3(8, 32, 2), 256, 0, stream>>>(
      xh, xl, WqT_h, WqT_l, WkT_h, WkT_l, bq, bk,
      nullptr, nullptr, qh, ql, kh, kl);
  // V (after qk so vbf can alias dead WqT/WkT). 512 blocks = 2/CU.
  gemm_big<1, 64><<<dim3(16, 32), 256, 0, stream>>>(
      xh, xl, WvT_h, WvT_l, nullptr, nullptr, bv, nullptr,
      nullptr, nullptr, vbf, nullptr, nullptr, nullptr);
  transpose_v<<<dim3(16, 64), 256, 0, stream>>>(vbf, vT);
  attn2<<<dim3(16, 64), 256, 0, stream>>>(qh, ql, kh, kl, vT, ctxh, ctxl);
  // O-proj + residual. 512 blocks = 2/CU.
  gemm_big<2, 64><<<dim3(16, 32), 256, 0, stream>>>(
      ctxh, ctxl, WoT_h, WoT_l, nullptr, nullptr, bo, nullptr,
      x, y_ws, nullptr, nullptr, nullptr, nullptr);
  ln_span<<<4096, 256, 0, stream>>>(y_ws, ln_g, ln_b, Ws, bs, lg_ws);
  final_kernel<<<16, 256, 0, stream>>>(lg_ws, eb, out);
}

// Round 5
// 277.626 us; speedup vs baseline: 1.5396x; 1.0525x over previous
//
#include <hip/hip_runtime.h>
#include <hip/hip_bf16.h>
#include <math.h>

typedef unsigned short ush;
typedef __attribute__((ext_vector_type(8))) short frag16;   // 8 bf16 = 4 VGPRs
typedef __attribute__((ext_vector_type(4))) float f32x4;

#define S_   1024
#define H_   1024
#define NH_  16
#define D_   64
#define L_   9
#define MB_  (1048576ull)

__device__ __forceinline__ ush bf16_rne(float x) {
  unsigned int b = __float_as_uint(x);
  b += 0x7FFFu + ((b >> 16) & 1u);
  return (ush)(b >> 16);
}
__device__ __forceinline__ void split2(float x, ush& h, ush& l) {
  h = bf16_rne(x);
  l = bf16_rne(x - __uint_as_float((unsigned int)h << 16));
}

// async global->LDS, 16B per lane; lds ptr must be wave-uniform base.
__device__ __forceinline__ void load_lds16(const ush* g, const ush* l) {
  __builtin_amdgcn_global_load_lds(
      (const __attribute__((address_space(1))) void*)g,
      (__attribute__((address_space(3))) void*)l, 16, 0, 0);
}

// ---------------------------------------------------------------------------
// Split + transpose 4 weights in one launch. W [k][n] fp32 -> WTh/WTl [n][k]
// bf16. Grid (16,16,4). (verified R10)
// ---------------------------------------------------------------------------
__global__ __launch_bounds__(256) void split_wT4(
    const float* W0, const float* W1, const float* W2, const float* W3,
    ush* h0, ush* l0, ush* h1, ush* l1, ush* h2, ush* l2, ush* h3, ush* l3) {
  __shared__ __align__(16) float Ls[64][68];
  const float* W = (blockIdx.z == 0) ? W0 : (blockIdx.z == 1) ? W1
                 : (blockIdx.z == 2) ? W2 : W3;
  ush* Th = (blockIdx.z == 0) ? h0 : (blockIdx.z == 1) ? h1
          : (blockIdx.z == 2) ? h2 : h3;
  ush* Tl = (blockIdx.z == 0) ? l0 : (blockIdx.z == 1) ? l1
          : (blockIdx.z == 2) ? l2 : l3;
  const int tid = threadIdx.x;
  const int n0 = blockIdx.x * 64, k0 = blockIdx.y * 64;
#pragma unroll
  for (int it = 0; it < 4; it++) {
    int flat = tid + 256 * it;
    int row = flat >> 4, nc = (flat & 15) * 4;
    *(float4*)&Ls[row][nc] = *(const float4*)&W[(size_t)(k0 + row) * 1024 + n0 + nc];
  }
  __syncthreads();
#pragma unroll
  for (int it = 0; it < 2; it++) {
    int flat = tid + 256 * it;
    int nrow = flat >> 3, kc = (flat & 7) * 8;
    ush hs[8], ls[8];
#pragma unroll
    for (int u = 0; u < 8; u++) split2(Ls[kc + u][nrow], hs[u], ls[u]);
    uint4 ph, pl;
    ph.x = hs[0] | ((unsigned)hs[1] << 16); ph.y = hs[2] | ((unsigned)hs[3] << 16);
    ph.z = hs[4] | ((unsigned)hs[5] << 16); ph.w = hs[6] | ((unsigned)hs[7] << 16);
    pl.x = ls[0] | ((unsigned)ls[1] << 16); pl.y = ls[2] | ((unsigned)ls[3] << 16);
    pl.z = ls[4] | ((unsigned)ls[5] << 16); pl.w = ls[6] | ((unsigned)ls[7] << 16);
    size_t o = (size_t)(n0 + nrow) * 1024 + k0 + kc;
    *(uint4*)&Th[o] = ph;
    *(uint4*)&Tl[o] = pl;
  }
}

// ---------------------------------------------------------------------------
// Pre-split x: fp32 [4096x1024] -> xh, xl bf16 row-major. Grid 2048.
// ---------------------------------------------------------------------------
__global__ __launch_bounds__(256) void split_x(
    const float* __restrict__ x, ush* __restrict__ xh, ush* __restrict__ xl) {
  const size_t i = ((size_t)blockIdx.x * 256 + threadIdx.x) * 8;
  float4 a = *(const float4*)&x[i];
  float4 b = *(const float4*)&x[i + 4];
  const float v[8] = {a.x, a.y, a.z, a.w, b.x, b.y, b.z, b.w};
  ush h[8], l[8];
#pragma unroll
  for (int u = 0; u < 8; u++) split2(v[u], h[u], l[u]);
  uint4 ph, pl;
  ph.x = h[0] | ((unsigned)h[1] << 16); ph.y = h[2] | ((unsigned)h[3] << 16);
  ph.z = h[4] | ((unsigned)h[5] << 16); ph.w = h[6] | ((unsigned)h[7] << 16);
  pl.x = l[0] | ((unsigned)l[1] << 16); pl.y = l[2] | ((unsigned)l[3] << 16);
  pl.z = l[4] | ((unsigned)l[5] << 16); pl.w = l[6] | ((unsigned)l[7] << 16);
  *(uint4*)&xh[i] = ph;
  *(uint4*)&xl[i] = pl;
}

// ---------------------------------------------------------------------------
// m97-structure split-bf16 GEMM + double-buffered prefetch (verified R4).
// EP: 0 = split bf16 out to head layout, z in {0,1} selects q/k set;
//     1 = bf16 out DIRECTLY TRANSPOSED to vT [bh][d][s] (packed ushort4 --
//         acc[r] covers 4 consecutive s for one d; bit-exact vs old
//         vbf+transpose path, saves the transpose dispatch);
//     2 = fp32 [m][n] + bias + residual (o-proj).
// ---------------------------------------------------------------------------
template <int EP, int BN>
__global__ __launch_bounds__(256) void gemm_big(
    const ush* __restrict__ Ah_g, const ush* __restrict__ Al_g,
    const ush* __restrict__ Bh0, const ush* __restrict__ Bl0,
    const ush* __restrict__ Bh1, const ush* __restrict__ Bl1,
    const float* __restrict__ bias0, const float* __restrict__ bias1,
    const float* __restrict__ resid, float* __restrict__ outf,
    ush* __restrict__ o0h, ush* __restrict__ o0l,
    ush* __restrict__ o1h, ush* __restrict__ o1l) {
  constexpr int NT = BN / 32;                    // frag cols per wave
  __shared__ __align__(16) ush As[2][2][128][32];  // [buf][hl][m][k]
  __shared__ __align__(16) ush Bs[2][2][BN][32];   // [buf][hl][n][k]
  const int tid = threadIdx.x, lane = tid & 63, wave = tid >> 6;
  const int l15 = lane & 15, quad = lane >> 4;
  const int m0 = blockIdx.y * 128, n0 = blockIdx.x * BN;

  const int z = (EP == 0) ? blockIdx.z : 0;
  const ush* Bh_g = z ? Bh1 : Bh0;
  const ush* Bl_g = z ? Bl1 : Bl0;
  const float* bias = z ? bias1 : bias0;
  ush* ohp = z ? o1h : o0h;
  ush* olp = z ? o1l : o0l;

  const int wm = (wave >> 1) * 64, wn = (wave & 1) * (BN / 2);

  f32x4 acc[4][NT];
#pragma unroll
  for (int i = 0; i < 4; i++)
#pragma unroll
    for (int j = 0; j < NT; j++) acc[i][j] = (f32x4){0.f, 0.f, 0.f, 0.f};

  // stage one BK=32 K-slab into buffer bi (async, copy-only)
  auto stage = [&](int bi, int k0) {
#pragma unroll
    for (int jj = 0; jj < 4; jj++) {
      const int call = wave * 4 + jj;
      const int c = call * 64 + lane;               // chunk id
      const int r = (c >> 2) & 127, ch = c & 3;     // row / 16B-chunk in row
      const ush* src = ((c >> 9) ? Al_g : Ah_g)
                     + (size_t)(m0 + r) * 1024 + k0 + ch * 8;
      load_lds16(src, &As[bi][0][0][0] + (size_t)call * 512);  // 1KB/call
    }
#pragma unroll
    for (int jj = 0; jj < NT; jj++) {
      const int call = wave * NT + jj;
      const int c = call * 64 + lane;
      const int r = (c >> 2) & (BN - 1), ch = c & 3;
      const ush* src = ((c >= BN * 4) ? Bl_g : Bh_g)
                     + (size_t)(n0 + r) * 1024 + k0 + ch * 8;
      load_lds16(src, &Bs[bi][0][0][0] + (size_t)call * 512);
    }
  };

  stage(0, 0);
  __syncthreads();   // buf0 staged

  for (int k0 = 0; k0 < 1024; k0 += 32) {
    const int cur = (k0 >> 5) & 1;
    if (k0 + 32 < 1024) stage(cur ^ 1, k0 + 32);   // prefetch, in flight

    frag16 a_h[4], a_l[4], b_h[NT], b_l[NT];
#pragma unroll
    for (int s = 0; s < 4; s++) {
      const int row = wm + s * 16 + l15;
      a_h[s] = *(const frag16*)&As[cur][0][row][quad * 8];
      a_l[s] = *(const frag16*)&As[cur][1][row][quad * 8];
    }
#pragma unroll
    for (int t = 0; t < NT; t++) {
      const int col = wn + t * 16 + l15;
      b_h[t] = *(const frag16*)&Bs[cur][0][col][quad * 8];
      b_l[t] = *(const frag16*)&Bs[cur][1][col][quad * 8];
    }
#pragma unroll
    for (int mi = 0; mi < 4; mi++)
#pragma unroll
      for (int ni = 0; ni < NT; ni++) {
        acc[mi][ni] = __builtin_amdgcn_mfma_f32_16x16x32_bf16(
            a_h[mi], b_h[ni], acc[mi][ni], 0, 0, 0);
        acc[mi][ni] = __builtin_amdgcn_mfma_f32_16x16x32_bf16(
            a_h[mi], b_l[ni], acc[mi][ni], 0, 0, 0);
        acc[mi][ni] = __builtin_amdgcn_mfma_f32_16x16x32_bf16(
            a_l[mi], b_h[ni], acc[mi][ni], 0, 0, 0);
      }
    __syncthreads();   // drains prefetch; all reads of cur done before reuse
  }

#pragma unroll
  for (int mi = 0; mi < 4; mi++) {
    const int rbase = m0 + wm + mi * 16 + quad * 4;
#pragma unroll
    for (int ni = 0; ni < NT; ni++) {
      const int col = n0 + wn + ni * 16 + l15;
      const float bv = bias[col];
      const int hidx = col >> 6, d = col & 63;
      if (EP == 1) {
        // direct-transposed vT write: 4 consecutive s for one (bh, d)
        const int bb = rbase >> 10, ss = rbase & 1023;
        ushort4 p4;
        p4.x = bf16_rne(acc[mi][ni][0] + bv);
        p4.y = bf16_rne(acc[mi][ni][1] + bv);
        p4.z = bf16_rne(acc[mi][ni][2] + bv);
        p4.w = bf16_rne(acc[mi][ni][3] + bv);
        *(ushort4*)&ohp[((size_t)(bb * NH_ + hidx) * D_ + d) * S_ + ss] = p4;
      } else {
#pragma unroll
        for (int r = 0; r < 4; r++) {
          const int m = rbase + r;
          float val = acc[mi][ni][r] + bv;
          if (EP == 2) {
            outf[(size_t)m * 1024 + col] = val + resid[(size_t)m * 1024 + col];
          } else {
            const int bb = m >> 10, ss = m & 1023;
            const size_t o = ((size_t)(bb * NH_ + hidx) * S_ + ss) * D_ + d;
            ush hh, ll;
            split2(val, hh, ll);
            ohp[o] = hh;
            olp[o] = ll;
          }
        }
      }
    }
  }
}

// ---------------------------------------------------------------------------
// MFMA flash attention, staged + window |j0-q0| <= 128 (excluded softmax
// mass <= ~5e-4 relative: scores carry -0.1*|i-j| pre-softmax) + LDS-LUT
// softmax: LUT[d] = (pb(d)*0.125 - 0.1*d - 20)*log2e, so per element
// sv = exp2(fma(score, K1, LUT[d])) -- one fma + one transcendental,
// no near/far branch. Fixed-max (M=20) is shift-invariant exact.
// LDS 36,864 + 1,024 B -> 4 blocks/CU.
// ---------------------------------------------------------------------------
__global__ __launch_bounds__(256) void attn2(
    const ush* __restrict__ qh, const ush* __restrict__ ql,
    const ush* __restrict__ kh, const ush* __restrict__ kl,
    const ush* __restrict__ vT,
    ush* __restrict__ ch, ush* __restrict__ cl) {
  __shared__ __align__(16) ush Kh[64][72], Kl[64][72];
  __shared__ __align__(16) ush VTs[64][72];   // [d][j]
  __shared__ __align__(16) ush Pst[64][72];   // [m][j]
  __shared__ float LUT[256];
  const int tid = threadIdx.x;
  const int lane = tid & 63, wave = tid >> 6;
  const int l15 = lane & 15, quad = lane >> 4;
  const int w16 = wave * 16;
  const int bh = blockIdx.y;
  const int b = bh >> 4, h = bh & 15;
  const int q0 = blockIdx.x * 64;

  const float K1 = 0.18033688011112042f;   // 0.125 * log2(e)
  const float K2 = 0.14426950408889634f;   // 0.1   * log2(e)

  // distance LUT (max dist at +/-128 window = 191 < 256)
  {
    const float dd = (float)tid;
    LUT[tid] = __expf(-0.1f * fminf(dd, 5.0f)) * K1 - dd * K2
             - 28.853900817779268f;        // 20*log2(e)
  }

  // ---- Q fragments straight from global (A-layout: m=l15, k=quad*8+j) ----
  const size_t qrow = ((size_t)bh * S_ + q0 + w16 + l15) * D_;
  frag16 a_h[2], a_l[2];
  a_h[0] = *(const frag16*)&qh[qrow + quad * 8];
  a_h[1] = *(const frag16*)&qh[qrow + 32 + quad * 8];
  a_l[0] = *(const frag16*)&ql[qrow + quad * 8];
  a_l[1] = *(const frag16*)&ql[qrow + 32 + quad * 8];

  f32x4 o[4];
  float lrow[4];
#pragma unroll
  for (int i = 0; i < 4; i++) {
    o[i] = (f32x4){0.f, 0.f, 0.f, 0.f};
    lrow[i] = 0.f;
  }

  const size_t kbase = (size_t)bh * S_ * D_;
  const size_t vbase = (size_t)bh * D_ * S_;

  // window: |j0 - q0| <= 128 (5 tiles interior)
  const int jlo = (q0 > 128) ? q0 - 128 : 0;
  const int jend = (q0 + 192 < S_) ? q0 + 192 : S_;

  for (int j0 = jlo; j0 < jend; j0 += 64) {
    __syncthreads();   // prior tile's frag reads done (also fences LUT fill)
#pragma unroll
    for (int it = 0; it < 2; it++) {
      const int flat = tid + 256 * it;
      const int row = flat >> 3, dc = (flat & 7) * 8;
      const size_t gk = kbase + (size_t)(j0 + row) * D_ + dc;
      *(uint4*)&Kh[row][dc] = *(const uint4*)&kh[gk];
      *(uint4*)&Kl[row][dc] = *(const uint4*)&kl[gk];
      *(uint4*)&VTs[row][dc] =
          *(const uint4*)&vT[vbase + (size_t)row * S_ + j0 + dc];
    }
    __syncthreads();

    // ---- S = Q.K^T (3-term split) ----
    f32x4 c4[4];
#pragma unroll
    for (int nt = 0; nt < 4; nt++) c4[nt] = (f32x4){0.f, 0.f, 0.f, 0.f};
#pragma unroll
    for (int kk = 0; kk < 2; kk++) {
#pragma unroll
      for (int nt = 0; nt < 4; nt++) {
        frag16 bh_ = *(const frag16*)&Kh[nt * 16 + l15][kk * 32 + quad * 8];
        frag16 bl_ = *(const frag16*)&Kl[nt * 16 + l15][kk * 32 + quad * 8];
        c4[nt] = __builtin_amdgcn_mfma_f32_16x16x32_bf16(a_h[kk], bh_, c4[nt], 0, 0, 0);
        c4[nt] = __builtin_amdgcn_mfma_f32_16x16x32_bf16(a_l[kk], bh_, c4[nt], 0, 0, 0);
        c4[nt] = __builtin_amdgcn_mfma_f32_16x16x32_bf16(a_h[kk], bl_, c4[nt], 0, 0, 0);
      }
    }

    // ---- LUT softmax + P store (C-layout: row=quad*4+r) ----
    const int ib = q0 + w16 + quad * 4 - j0 - l15;
#pragma unroll
    for (int r = 0; r < 4; r++) {
#pragma unroll
      for (int nt = 0; nt < 4; nt++) {
        int di = ib + r - nt * 16;
        di = (di < 0) ? -di : di;
        const float sv = exp2f(fmaf(c4[nt][r], K1, LUT[di]));
        lrow[r] += sv;
        Pst[w16 + quad * 4 + r][nt * 16 + l15] = bf16_rne(sv);
      }
    }

    // ---- PV (own rows only; same-wave LDS ordering, no barrier) ----
    frag16 pa[2];
    pa[0] = *(const frag16*)&Pst[w16 + l15][quad * 8];
    pa[1] = *(const frag16*)&Pst[w16 + l15][32 + quad * 8];
#pragma unroll
    for (int dt = 0; dt < 4; dt++) {
      frag16 vb0 = *(const frag16*)&VTs[dt * 16 + l15][quad * 8];
      frag16 vb1 = *(const frag16*)&VTs[dt * 16 + l15][32 + quad * 8];
      o[dt] = __builtin_amdgcn_mfma_f32_16x16x32_bf16(pa[0], vb0, o[dt], 0, 0, 0);
      o[dt] = __builtin_amdgcn_mfma_f32_16x16x32_bf16(pa[1], vb1, o[dt], 0, 0, 0);
    }
  }

  // ---- deferred row-sum reduction + normalize + write pre-split ctx ----
#pragma unroll
  for (int r = 0; r < 4; r++) {
#pragma unroll
    for (int off = 1; off < 16; off <<= 1) lrow[r] += __shfl_xor(lrow[r], off);
    const float inv = 1.0f / lrow[r];
    const size_t rowp =
        ((size_t)(b * S_ + q0 + w16 + quad * 4 + r)) * H_ + h * 64;
#pragma unroll
    for (int dt = 0; dt < 4; dt++) {
      ush hh, ll;
      split2(o[dt][r] * inv, hh, ll);
      ch[rowp + dt * 16 + l15] = hh;
      cl[rowp + dt * 16 + l15] = ll;
    }
  }
}

// ---------------------------------------------------------------------------
// Fused LayerNorm + span logits: one block per row. (verified R10)
// ---------------------------------------------------------------------------
__global__ __launch_bounds__(256) void ln_span(
    const float* __restrict__ y, const float* __restrict__ g,
    const float* __restrict__ bta, const float* __restrict__ Wsp,
    const float* __restrict__ bs, float* __restrict__ logits) {
  const int row = blockIdx.x;
  const int tid = threadIdx.x, lane = tid & 63, wave = tid >> 6;
  const float* yr = y + (size_t)row * 1024;
  float vals[4], s = 0.f, s2 = 0.f;
#pragma unroll
  for (int i = 0; i < 4; i++) {
    float t = yr[tid + i * 256];
    vals[i] = t; s += t; s2 += t * t;
  }
#pragma unroll
  for (int off = 32; off; off >>= 1) {
    s += __shfl_xor(s, off);
    s2 += __shfl_xor(s2, off);
  }
  __shared__ float red[8];
  __shared__ float red9[4][12];
  if (lane == 0) { red[wave] = s; red[4 + wave] = s2; }
  __syncthreads();
  s = red[0] + red[1] + red[2] + red[3];
  s2 = red[4] + red[5] + red[6] + red[7];
  const float mu = s * (1.0f / 1024.0f);
  const float var = s2 * (1.0f / 1024.0f) - mu * mu;
  const float inv = rsqrtf(var + 1e-5f);

  float lg[9];
#pragma unroll
  for (int l = 0; l < 9; l++) lg[l] = 0.f;
#pragma unroll
  for (int i = 0; i < 4; i++) {
    const int hh = tid + i * 256;
    const float yn = (vals[i] - mu) * inv * g[hh] + bta[hh];
#pragma unroll
    for (int l = 0; l < 9; l++) lg[l] += yn * Wsp[hh * 9 + l];
  }
#pragma unroll
  for (int l = 0; l < 9; l++) {
#pragma unroll
    for (int off = 32; off; off >>= 1) lg[l] += __shfl_xor(lg[l], off);
  }
  if (lane == 0) {
#pragma unroll
    for (int l = 0; l < 9; l++) red9[wave][l] = lg[l];
  }
  __syncthreads();
  if (tid < 9) {
    logits[(size_t)row * 9 + tid] =
        red9[0][tid] + red9[1][tid] + red9[2][tid] + red9[3][tid] + bs[tid];
  }
}

// ---------------------------------------------------------------------------
// Entity-bias adjustment + FP32 output. One thread per token.
// ---------------------------------------------------------------------------
__global__ __launch_bounds__(256) void final_kernel(
    const float* __restrict__ logits, const float* __restrict__ eb,
    float* __restrict__ out) {
  const int m = blockIdx.x * 256 + threadIdx.x;
  const int i = m & 1023;
  float cur[9];
#pragma unroll
  for (int l = 0; l < 9; l++) cur[l] = logits[(size_t)m * 9 + l];
  if (i > 0) {
    const float* prev = logits + (size_t)(m - 1) * 9;
    int am = 0;
    float best = prev[0];
#pragma unroll
    for (int l = 1; l < 9; l++) {
      float pv = prev[l];
      if (pv > best) { best = pv; am = l; }
    }
    if (am == 1) cur[2] += 2.0f * eb[2];
  }
#pragma unroll
  for (int l = 0; l < 9; l++) out[(size_t)m * 9 + l] = cur[l];
}

// ---------------------------------------------------------------------------
extern "C" void kernel_launch(void* const* d_in, const int* in_sizes, int n_in,
                              void* d_out, int out_size, void* d_ws, size_t ws_size,
                              hipStream_t stream) {
  const float* x    = (const float*)d_in[0];
  const float* Wq   = (const float*)d_in[1];
  const float* bq   = (const float*)d_in[2];
  const float* Wk   = (const float*)d_in[3];
  const float* bk   = (const float*)d_in[4];
  const float* Wv   = (const float*)d_in[5];
  const float* bv   = (const float*)d_in[6];
  const float* Wo   = (const float*)d_in[7];
  const float* bo   = (const float*)d_in[8];
  const float* ln_g = (const float*)d_in[9];
  const float* ln_b = (const float*)d_in[10];
  const float* Ws   = (const float*)d_in[11];
  const float* bs   = (const float*)d_in[12];
  const float* eb   = (const float*)d_in[13];
  float* out = (float*)d_out;
  char* W8 = (char*)d_ws;

  // ---- ws layout, 64 MB envelope with phase-aliasing ----
  // [0,4):   WoT h+l            (alive until O-proj)
  // [4,8):   WqT h+l            (dead after qk-gemm dispatch)
  // [8,12):  WkT h+l            (dead after qk-gemm dispatch)
  // [12,16): WvT h+l            (dead after v-gemm)
  // [16,24): xh   [24,32): xl   (dead after v-gemm)
  // [32,40): qh   [40,48): ql   (dead after attn)
  // [48,56): kh   [56,64): kl   (dead after attn)
  ush* WoT_h = (ush*)(W8 + 0 * MB_);
  ush* WoT_l = (ush*)(W8 + 2 * MB_);
  ush* WqT_h = (ush*)(W8 + 4 * MB_);
  ush* WqT_l = (ush*)(W8 + 6 * MB_);
  ush* WkT_h = (ush*)(W8 + 8 * MB_);
  ush* WkT_l = (ush*)(W8 + 10 * MB_);
  ush* WvT_h = (ush*)(W8 + 12 * MB_);
  ush* WvT_l = (ush*)(W8 + 14 * MB_);
  ush* xh    = (ush*)(W8 + 16 * MB_);
  ush* xl    = (ush*)(W8 + 24 * MB_);
  ush* qh    = (ush*)(W8 + 32 * MB_);
  ush* ql    = (ush*)(W8 + 40 * MB_);
  ush* kh    = (ush*)(W8 + 48 * MB_);
  ush* kl    = (ush*)(W8 + 56 * MB_);
  // aliases:
  ush*   vT   = (ush*)(W8 + 4 * MB_);    // over WqT+WkT (dead after qk), 8 MB
                                         //   written directly by V-gemm EP=1
  ush*   ctxl = (ush*)(W8 + 16 * MB_);   // over xh (dead after v-gemm)
  ush*   ctxh = (ush*)(W8 + 24 * MB_);   // over xl (dead after v-gemm)
  float* y_ws = (float*)(W8 + 32 * MB_); // over qh/ql (dead after attn)
  float* lg_ws = (float*)(W8 + 48 * MB_);// over kh (dead after attn)

  split_wT4<<<dim3(16, 16, 4), 256, 0, stream>>>(
      Wq, Wk, Wv, Wo, WqT_h, WqT_l, WkT_h, WkT_l, WvT_h, WvT_l, WoT_h, WoT_l);
  split_x<<<2048, 256, 0, stream>>>(x, xh, xl);

  // Q+K fused: z selects {Wq->qh/ql, Wk->kh/kl}. 512 blocks = 2/CU.
  gemm_big<0, 128><<<dim3(8, 32, 2), 256, 0, stream>>>(
      xh, xl, WqT_h, WqT_l, WkT_h, WkT_l, bq, bk,
      nullptr, nullptr, qh, ql, kh, kl);
  // V, direct-transposed output into vT (over dead WqT/WkT). 512 blocks.
  gemm_big<1, 64><<<dim3(16, 32), 256, 0, stream>>>(
      xh, xl, WvT_h, WvT_l, nullptr, nullptr, bv, nullptr,
      nullptr, nullptr, vT, nullptr, nullptr, nullptr);
  attn2<<<dim3(16, 64), 256, 0, stream>>>(qh, ql, kh, kl, vT, ctxh, ctxl);
  // O-proj + residual. 512 blocks = 2/CU.
  gemm_big<2, 64><<<dim3(16, 32), 256, 0, stream>>>(
      ctxh, ctxl, WoT_h, WoT_l, nullptr, nullptr, bo, nullptr,
      x, y_ws, nullptr, nullptr, nullptr, nullptr);
  ln_span<<<4096, 256, 0, stream>>>(y_ws, ln_g, ln_b, Ws, bs, lg_ws);
  final_kernel<<<16, 256, 0, stream>>>(lg_ws, eb, out);
}

// Round 6
// 244.485 us; speedup vs baseline: 1.7483x; 1.1356x over previous
//
#include <hip/hip_runtime.h>
#include <hip/hip_bf16.h>
#include <math.h>

typedef unsigned short ush;
typedef __attribute__((ext_vector_type(8))) short frag16;   // 8 bf16 = 4 VGPRs
typedef __attribute__((ext_vector_type(4))) float f32x4;

#define S_   1024
#define H_   1024
#define NH_  16
#define D_   64
#define L_   9
#define MB_  (1048576ull)

__device__ __forceinline__ ush bf16_rne(float x) {
  unsigned int b = __float_as_uint(x);
  b += 0x7FFFu + ((b >> 16) & 1u);
  return (ush)(b >> 16);
}
__device__ __forceinline__ void split2(float x, ush& h, ush& l) {
  h = bf16_rne(x);
  l = bf16_rne(x - __uint_as_float((unsigned int)h << 16));
}

// async global->LDS, 16B per lane; lds ptr must be wave-uniform base.
__device__ __forceinline__ void load_lds16(const ush* g, const ush* l) {
  __builtin_amdgcn_global_load_lds(
      (const __attribute__((address_space(1))) void*)g,
      (__attribute__((address_space(3))) void*)l, 16, 0, 0);
}

// ---------------------------------------------------------------------------
// Split + transpose 4 weights in one launch. W [k][n] fp32 -> WTh/WTl [n][k]
// bf16. Grid (16,16,4). Weights KEEP the h+l split (B-side 2-term GEMM
// kills weight-quantization error; activation-side low bits dropped --
// see precision budget in session notes R6).
// ---------------------------------------------------------------------------
__global__ __launch_bounds__(256) void split_wT4(
    const float* W0, const float* W1, const float* W2, const float* W3,
    ush* h0, ush* l0, ush* h1, ush* l1, ush* h2, ush* l2, ush* h3, ush* l3) {
  __shared__ __align__(16) float Ls[64][68];
  const float* W = (blockIdx.z == 0) ? W0 : (blockIdx.z == 1) ? W1
                 : (blockIdx.z == 2) ? W2 : W3;
  ush* Th = (blockIdx.z == 0) ? h0 : (blockIdx.z == 1) ? h1
          : (blockIdx.z == 2) ? h2 : h3;
  ush* Tl = (blockIdx.z == 0) ? l0 : (blockIdx.z == 1) ? l1
          : (blockIdx.z == 2) ? l2 : l3;
  const int tid = threadIdx.x;
  const int n0 = blockIdx.x * 64, k0 = blockIdx.y * 64;
#pragma unroll
  for (int it = 0; it < 4; it++) {
    int flat = tid + 256 * it;
    int row = flat >> 4, nc = (flat & 15) * 4;
    *(float4*)&Ls[row][nc] = *(const float4*)&W[(size_t)(k0 + row) * 1024 + n0 + nc];
  }
  __syncthreads();
#pragma unroll
  for (int it = 0; it < 2; it++) {
    int flat = tid + 256 * it;
    int nrow = flat >> 3, kc = (flat & 7) * 8;
    ush hs[8], ls[8];
#pragma unroll
    for (int u = 0; u < 8; u++) split2(Ls[kc + u][nrow], hs[u], ls[u]);
    uint4 ph, pl;
    ph.x = hs[0] | ((unsigned)hs[1] << 16); ph.y = hs[2] | ((unsigned)hs[3] << 16);
    ph.z = hs[4] | ((unsigned)hs[5] << 16); ph.w = hs[6] | ((unsigned)hs[7] << 16);
    pl.x = ls[0] | ((unsigned)ls[1] << 16); pl.y = ls[2] | ((unsigned)ls[3] << 16);
    pl.z = ls[4] | ((unsigned)ls[5] << 16); pl.w = ls[6] | ((unsigned)ls[7] << 16);
    size_t o = (size_t)(n0 + nrow) * 1024 + k0 + kc;
    *(uint4*)&Th[o] = ph;
    *(uint4*)&Tl[o] = pl;
  }
}

// ---------------------------------------------------------------------------
// Cast x: fp32 [4096x1024] -> xh bf16 rne (no low-part: activation lows
// dropped per the 2-term budget). Grid 2048.
// ---------------------------------------------------------------------------
__global__ __launch_bounds__(256) void cast_x(
    const float* __restrict__ x, ush* __restrict__ xh) {
  const size_t i = ((size_t)blockIdx.x * 256 + threadIdx.x) * 8;
  float4 a = *(const float4*)&x[i];
  float4 b = *(const float4*)&x[i + 4];
  const float v[8] = {a.x, a.y, a.z, a.w, b.x, b.y, b.z, b.w};
  ush h[8];
#pragma unroll
  for (int u = 0; u < 8; u++) h[u] = bf16_rne(v[u]);
  uint4 ph;
  ph.x = h[0] | ((unsigned)h[1] << 16); ph.y = h[2] | ((unsigned)h[3] << 16);
  ph.z = h[4] | ((unsigned)h[5] << 16); ph.w = h[6] | ((unsigned)h[7] << 16);
  *(uint4*)&xh[i] = ph;
}

// ---------------------------------------------------------------------------
// Fused QKV GEMM: A = xh (single bf16), B = weight h+l split, 2-term
// (ah*bh + ah*bl). 128x128 tile, BK=32, double-buffered global_load_lds.
// z in {0,1,2} selects {Wq->qh, Wk->kh, Wv->vT(transposed epilogue)}.
// LDS 48KB -> 3 blocks/CU; grid (8,32,3) = 768 = 3/CU exactly.
// ---------------------------------------------------------------------------
__global__ __launch_bounds__(256) void gemm_qkv(
    const ush* __restrict__ xh,
    const ush* __restrict__ Bq_h, const ush* __restrict__ Bq_l,
    const ush* __restrict__ Bk_h, const ush* __restrict__ Bk_l,
    const ush* __restrict__ Bv_h, const ush* __restrict__ Bv_l,
    const float* __restrict__ bq, const float* __restrict__ bk,
    const float* __restrict__ bv,
    ush* __restrict__ qh, ush* __restrict__ kh, ush* __restrict__ vT) {
  __shared__ __align__(16) ush As[2][128][32];      // [buf][m][k]
  __shared__ __align__(16) ush Bs[2][2][128][32];   // [buf][hl][n][k]
  const int tid = threadIdx.x, lane = tid & 63, wave = tid >> 6;
  const int l15 = lane & 15, quad = lane >> 4;
  const int m0 = blockIdx.y * 128, n0 = blockIdx.x * 128;
  const int z = blockIdx.z;
  const ush* Bh_g = (z == 0) ? Bq_h : (z == 1) ? Bk_h : Bv_h;
  const ush* Bl_g = (z == 0) ? Bq_l : (z == 1) ? Bk_l : Bv_l;
  const float* bias = (z == 0) ? bq : (z == 1) ? bk : bv;
  ush* outp = (z == 0) ? qh : (z == 1) ? kh : vT;

  const int wm = (wave >> 1) * 64, wn = (wave & 1) * 64;

  f32x4 acc[4][4];
#pragma unroll
  for (int i = 0; i < 4; i++)
#pragma unroll
    for (int j = 0; j < 4; j++) acc[i][j] = (f32x4){0.f, 0.f, 0.f, 0.f};

  auto stage = [&](int bi, int k0) {
#pragma unroll
    for (int jj = 0; jj < 2; jj++) {          // A: 8 KB = 8 wave-calls
      const int call = wave * 2 + jj;
      const int c = call * 64 + lane;         // chunk in [0,512)
      const int r = c >> 2, ch = c & 3;
      const ush* src = xh + (size_t)(m0 + r) * 1024 + k0 + ch * 8;
      load_lds16(src, &As[bi][0][0] + (size_t)call * 512);
    }
#pragma unroll
    for (int jj = 0; jj < 4; jj++) {          // B: 16 KB = 16 wave-calls
      const int call = wave * 4 + jj;
      const int c = call * 64 + lane;         // chunk in [0,1024)
      const int r = (c >> 2) & 127, ch = c & 3;
      const ush* src = ((c >= 512) ? Bl_g : Bh_g)
                     + (size_t)(n0 + r) * 1024 + k0 + ch * 8;
      load_lds16(src, &Bs[bi][0][0][0] + (size_t)call * 512);
    }
  };

  stage(0, 0);
  __syncthreads();

  for (int k0 = 0; k0 < 1024; k0 += 32) {
    const int cur = (k0 >> 5) & 1;
    if (k0 + 32 < 1024) stage(cur ^ 1, k0 + 32);

    frag16 a_h[4], b_h[4], b_l[4];
#pragma unroll
    for (int s = 0; s < 4; s++)
      a_h[s] = *(const frag16*)&As[cur][wm + s * 16 + l15][quad * 8];
#pragma unroll
    for (int t = 0; t < 4; t++) {
      const int col = wn + t * 16 + l15;
      b_h[t] = *(const frag16*)&Bs[cur][0][col][quad * 8];
      b_l[t] = *(const frag16*)&Bs[cur][1][col][quad * 8];
    }
#pragma unroll
    for (int mi = 0; mi < 4; mi++)
#pragma unroll
      for (int ni = 0; ni < 4; ni++) {
        acc[mi][ni] = __builtin_amdgcn_mfma_f32_16x16x32_bf16(
            a_h[mi], b_h[ni], acc[mi][ni], 0, 0, 0);
        acc[mi][ni] = __builtin_amdgcn_mfma_f32_16x16x32_bf16(
            a_h[mi], b_l[ni], acc[mi][ni], 0, 0, 0);
      }
    __syncthreads();
  }

#pragma unroll
  for (int mi = 0; mi < 4; mi++) {
    const int rbase = m0 + wm + mi * 16 + quad * 4;
    const int bb = rbase >> 10, ss = rbase & 1023;
#pragma unroll
    for (int ni = 0; ni < 4; ni++) {
      const int col = n0 + wn + ni * 16 + l15;
      const float bv_ = bias[col];
      const int hidx = col >> 6, d = col & 63;
      if (z == 2) {
        // V: direct-transposed vT [bh][d][s], 4 consecutive s packed
        ushort4 p4;
        p4.x = bf16_rne(acc[mi][ni][0] + bv_);
        p4.y = bf16_rne(acc[mi][ni][1] + bv_);
        p4.z = bf16_rne(acc[mi][ni][2] + bv_);
        p4.w = bf16_rne(acc[mi][ni][3] + bv_);
        *(ushort4*)&outp[((size_t)(bb * NH_ + hidx) * D_ + d) * S_ + ss] = p4;
      } else {
#pragma unroll
        for (int r = 0; r < 4; r++) {
          const size_t o =
              ((size_t)(bb * NH_ + hidx) * S_ + (ss + r)) * D_ + d;
          outp[o] = bf16_rne(acc[mi][ni][r] + bv_);
        }
      }
    }
  }
}

// ---------------------------------------------------------------------------
// O-projection GEMM: A = ctxh (single bf16), B = WoT h+l, 2-term.
// 128x64 tile; fp32 out + bias + residual. LDS 32KB. Grid (16,32) = 512.
// ---------------------------------------------------------------------------
__global__ __launch_bounds__(256) void gemm_o(
    const ush* __restrict__ ctxh,
    const ush* __restrict__ Boh, const ush* __restrict__ Bol,
    const float* __restrict__ bo, const float* __restrict__ resid,
    float* __restrict__ outf) {
  __shared__ __align__(16) ush As[2][128][32];     // [buf][m][k]
  __shared__ __align__(16) ush Bs[2][2][64][32];   // [buf][hl][n][k]
  const int tid = threadIdx.x, lane = tid & 63, wave = tid >> 6;
  const int l15 = lane & 15, quad = lane >> 4;
  const int m0 = blockIdx.y * 128, n0 = blockIdx.x * 64;
  const int wm = (wave >> 1) * 64, wn = (wave & 1) * 32;

  f32x4 acc[4][2];
#pragma unroll
  for (int i = 0; i < 4; i++)
#pragma unroll
    for (int j = 0; j < 2; j++) acc[i][j] = (f32x4){0.f, 0.f, 0.f, 0.f};

  auto stage = [&](int bi, int k0) {
#pragma unroll
    for (int jj = 0; jj < 2; jj++) {          // A: 8 wave-calls
      const int call = wave * 2 + jj;
      const int c = call * 64 + lane;
      const int r = c >> 2, ch = c & 3;
      const ush* src = ctxh + (size_t)(m0 + r) * 1024 + k0 + ch * 8;
      load_lds16(src, &As[bi][0][0] + (size_t)call * 512);
    }
#pragma unroll
    for (int jj = 0; jj < 2; jj++) {          // B: 8 wave-calls
      const int call = wave * 2 + jj;
      const int c = call * 64 + lane;         // chunk in [0,512)
      const int r = (c >> 2) & 63, ch = c & 3;
      const ush* src = ((c >= 256) ? Bol : Boh)
                     + (size_t)(n0 + r) * 1024 + k0 + ch * 8;
      load_lds16(src, &Bs[bi][0][0][0] + (size_t)call * 512);
    }
  };

  stage(0, 0);
  __syncthreads();

  for (int k0 = 0; k0 < 1024; k0 += 32) {
    const int cur = (k0 >> 5) & 1;
    if (k0 + 32 < 1024) stage(cur ^ 1, k0 + 32);

    frag16 a_h[4], b_h[2], b_l[2];
#pragma unroll
    for (int s = 0; s < 4; s++)
      a_h[s] = *(const frag16*)&As[cur][wm + s * 16 + l15][quad * 8];
#pragma unroll
    for (int t = 0; t < 2; t++) {
      const int col = wn + t * 16 + l15;
      b_h[t] = *(const frag16*)&Bs[cur][0][col][quad * 8];
      b_l[t] = *(const frag16*)&Bs[cur][1][col][quad * 8];
    }
#pragma unroll
    for (int mi = 0; mi < 4; mi++)
#pragma unroll
      for (int ni = 0; ni < 2; ni++) {
        acc[mi][ni] = __builtin_amdgcn_mfma_f32_16x16x32_bf16(
            a_h[mi], b_h[ni], acc[mi][ni], 0, 0, 0);
        acc[mi][ni] = __builtin_amdgcn_mfma_f32_16x16x32_bf16(
            a_h[mi], b_l[ni], acc[mi][ni], 0, 0, 0);
      }
    __syncthreads();
  }

#pragma unroll
  for (int mi = 0; mi < 4; mi++) {
    const int rbase = m0 + wm + mi * 16 + quad * 4;
#pragma unroll
    for (int ni = 0; ni < 2; ni++) {
      const int col = n0 + wn + ni * 16 + l15;
      const float bv_ = bo[col];
#pragma unroll
      for (int r = 0; r < 4; r++) {
        const int m = rbase + r;
        outf[(size_t)m * 1024 + col] =
            acc[mi][ni][r] + bv_ + resid[(size_t)m * 1024 + col];
      }
    }
  }
}

// ---------------------------------------------------------------------------
// MFMA flash attention: single-bf16 Q,K (1-term QK^T: score error ~9e-3,
// -> P rel err ~1e-3, below P's own bf16-storage noise), window
// |j0-q0| <= 128, LDS-LUT softmax, fixed-max (M=20). Single-bf16 ctx out.
// LDS ~28.7KB -> 4 blocks/CU (grid-limited).
// ---------------------------------------------------------------------------
__global__ __launch_bounds__(256) void attn2(
    const ush* __restrict__ qh, const ush* __restrict__ kh,
    const ush* __restrict__ vT, ush* __restrict__ ch) {
  __shared__ __align__(16) ush Kh[64][72];
  __shared__ __align__(16) ush VTs[64][72];   // [d][j]
  __shared__ __align__(16) ush Pst[64][72];   // [m][j]
  __shared__ float LUT[256];
  const int tid = threadIdx.x;
  const int lane = tid & 63, wave = tid >> 6;
  const int l15 = lane & 15, quad = lane >> 4;
  const int w16 = wave * 16;
  const int bh = blockIdx.y;
  const int b = bh >> 4, h = bh & 15;
  const int q0 = blockIdx.x * 64;

  const float K1 = 0.18033688011112042f;   // 0.125 * log2(e)
  const float K2 = 0.14426950408889634f;   // 0.1   * log2(e)
  {
    const float dd = (float)tid;
    LUT[tid] = __expf(-0.1f * fminf(dd, 5.0f)) * K1 - dd * K2
             - 28.853900817779268f;        // 20*log2(e)
  }

  const size_t qrow = ((size_t)bh * S_ + q0 + w16 + l15) * D_;
  frag16 a_h[2];
  a_h[0] = *(const frag16*)&qh[qrow + quad * 8];
  a_h[1] = *(const frag16*)&qh[qrow + 32 + quad * 8];

  f32x4 o[4];
  float lrow[4];
#pragma unroll
  for (int i = 0; i < 4; i++) {
    o[i] = (f32x4){0.f, 0.f, 0.f, 0.f};
    lrow[i] = 0.f;
  }

  const size_t kbase = (size_t)bh * S_ * D_;
  const size_t vbase = (size_t)bh * D_ * S_;

  const int jlo = (q0 > 128) ? q0 - 128 : 0;
  const int jend = (q0 + 192 < S_) ? q0 + 192 : S_;

  for (int j0 = jlo; j0 < jend; j0 += 64) {
    __syncthreads();   // prior tile's frag reads done (also fences LUT)
#pragma unroll
    for (int it = 0; it < 2; it++) {
      const int flat = tid + 256 * it;
      const int row = flat >> 3, dc = (flat & 7) * 8;
      *(uint4*)&Kh[row][dc] =
          *(const uint4*)&kh[kbase + (size_t)(j0 + row) * D_ + dc];
      *(uint4*)&VTs[row][dc] =
          *(const uint4*)&vT[vbase + (size_t)row * S_ + j0 + dc];
    }
    __syncthreads();

    // ---- S = Q.K^T (single term) ----
    f32x4 c4[4];
#pragma unroll
    for (int nt = 0; nt < 4; nt++) c4[nt] = (f32x4){0.f, 0.f, 0.f, 0.f};
#pragma unroll
    for (int kk = 0; kk < 2; kk++) {
#pragma unroll
      for (int nt = 0; nt < 4; nt++) {
        frag16 bh_ = *(const frag16*)&Kh[nt * 16 + l15][kk * 32 + quad * 8];
        c4[nt] = __builtin_amdgcn_mfma_f32_16x16x32_bf16(a_h[kk], bh_, c4[nt], 0, 0, 0);
      }
    }

    // ---- LUT softmax + P store (C-layout: row=quad*4+r) ----
    const int ib = q0 + w16 + quad * 4 - j0 - l15;
#pragma unroll
    for (int r = 0; r < 4; r++) {
#pragma unroll
      for (int nt = 0; nt < 4; nt++) {
        int di = ib + r - nt * 16;
        di = (di < 0) ? -di : di;
        const float sv = exp2f(fmaf(c4[nt][r], K1, LUT[di]));
        lrow[r] += sv;
        Pst[w16 + quad * 4 + r][nt * 16 + l15] = bf16_rne(sv);
      }
    }

    // ---- PV (own rows only; same-wave LDS ordering, no barrier) ----
    frag16 pa[2];
    pa[0] = *(const frag16*)&Pst[w16 + l15][quad * 8];
    pa[1] = *(const frag16*)&Pst[w16 + l15][32 + quad * 8];
#pragma unroll
    for (int dt = 0; dt < 4; dt++) {
      frag16 vb0 = *(const frag16*)&VTs[dt * 16 + l15][quad * 8];
      frag16 vb1 = *(const frag16*)&VTs[dt * 16 + l15][32 + quad * 8];
      o[dt] = __builtin_amdgcn_mfma_f32_16x16x32_bf16(pa[0], vb0, o[dt], 0, 0, 0);
      o[dt] = __builtin_amdgcn_mfma_f32_16x16x32_bf16(pa[1], vb1, o[dt], 0, 0, 0);
    }
  }

  // ---- deferred row-sum reduction + normalize + write bf16 ctx ----
#pragma unroll
  for (int r = 0; r < 4; r++) {
#pragma unroll
    for (int off = 1; off < 16; off <<= 1) lrow[r] += __shfl_xor(lrow[r], off);
    const float inv = 1.0f / lrow[r];
    const size_t rowp =
        ((size_t)(b * S_ + q0 + w16 + quad * 4 + r)) * H_ + h * 64;
#pragma unroll
    for (int dt = 0; dt < 4; dt++)
      ch[rowp + dt * 16 + l15] = bf16_rne(o[dt][r] * inv);
  }
}

// ---------------------------------------------------------------------------
// Fused LayerNorm + span logits: one block per row. (verified R10)
// ---------------------------------------------------------------------------
__global__ __launch_bounds__(256) void ln_span(
    const float* __restrict__ y, const float* __restrict__ g,
    const float* __restrict__ bta, const float* __restrict__ Wsp,
    const float* __restrict__ bs, float* __restrict__ logits) {
  const int row = blockIdx.x;
  const int tid = threadIdx.x, lane = tid & 63, wave = tid >> 6;
  const float* yr = y + (size_t)row * 1024;
  float vals[4], s = 0.f, s2 = 0.f;
#pragma unroll
  for (int i = 0; i < 4; i++) {
    float t = yr[tid + i * 256];
    vals[i] = t; s += t; s2 += t * t;
  }
#pragma unroll
  for (int off = 32; off; off >>= 1) {
    s += __shfl_xor(s, off);
    s2 += __shfl_xor(s2, off);
  }
  __shared__ float red[8];
  __shared__ float red9[4][12];
  if (lane == 0) { red[wave] = s; red[4 + wave] = s2; }
  __syncthreads();
  s = red[0] + red[1] + red[2] + red[3];
  s2 = red[4] + red[5] + red[6] + red[7];
  const float mu = s * (1.0f / 1024.0f);
  const float var = s2 * (1.0f / 1024.0f) - mu * mu;
  const float inv = rsqrtf(var + 1e-5f);

  float lg[9];
#pragma unroll
  for (int l = 0; l < 9; l++) lg[l] = 0.f;
#pragma unroll
  for (int i = 0; i < 4; i++) {
    const int hh = tid + i * 256;
    const float yn = (vals[i] - mu) * inv * g[hh] + bta[hh];
#pragma unroll
    for (int l = 0; l < 9; l++) lg[l] += yn * Wsp[hh * 9 + l];
  }
#pragma unroll
  for (int l = 0; l < 9; l++) {
#pragma unroll
    for (int off = 32; off; off >>= 1) lg[l] += __shfl_xor(lg[l], off);
  }
  if (lane == 0) {
#pragma unroll
    for (int l = 0; l < 9; l++) red9[wave][l] = lg[l];
  }
  __syncthreads();
  if (tid < 9) {
    logits[(size_t)row * 9 + tid] =
        red9[0][tid] + red9[1][tid] + red9[2][tid] + red9[3][tid] + bs[tid];
  }
}

// ---------------------------------------------------------------------------
// Entity-bias adjustment + FP32 output. One thread per token.
// ---------------------------------------------------------------------------
__global__ __launch_bounds__(256) void final_kernel(
    const float* __restrict__ logits, const float* __restrict__ eb,
    float* __restrict__ out) {
  const int m = blockIdx.x * 256 + threadIdx.x;
  const int i = m & 1023;
  float cur[9];
#pragma unroll
  for (int l = 0; l < 9; l++) cur[l] = logits[(size_t)m * 9 + l];
  if (i > 0) {
    const float* prev = logits + (size_t)(m - 1) * 9;
    int am = 0;
    float best = prev[0];
#pragma unroll
    for (int l = 1; l < 9; l++) {
      float pv = prev[l];
      if (pv > best) { best = pv; am = l; }
    }
    if (am == 1) cur[2] += 2.0f * eb[2];
  }
#pragma unroll
  for (int l = 0; l < 9; l++) out[(size_t)m * 9 + l] = cur[l];
}

// ---------------------------------------------------------------------------
extern "C" void kernel_launch(void* const* d_in, const int* in_sizes, int n_in,
                              void* d_out, int out_size, void* d_ws, size_t ws_size,
                              hipStream_t stream) {
  const float* x    = (const float*)d_in[0];
  const float* Wq   = (const float*)d_in[1];
  const float* bq   = (const float*)d_in[2];
  const float* Wk   = (const float*)d_in[3];
  const float* bk   = (const float*)d_in[4];
  const float* Wv   = (const float*)d_in[5];
  const float* bv   = (const float*)d_in[6];
  const float* Wo   = (const float*)d_in[7];
  const float* bo   = (const float*)d_in[8];
  const float* ln_g = (const float*)d_in[9];
  const float* ln_b = (const float*)d_in[10];
  const float* Ws   = (const float*)d_in[11];
  const float* bs   = (const float*)d_in[12];
  const float* eb   = (const float*)d_in[13];
  float* out = (float*)d_out;
  char* W8 = (char*)d_ws;

  // ---- ws layout (64 MB envelope, activations single-bf16) ----
  // [0,4):   WoT h+l   (alive until O-proj)
  // [4,8):   WqT h+l   [8,12): WkT h+l   [12,16): WvT h+l
  // [16,24): xh        (dead after qkv-gemm)
  // [24,32): qh        [32,40): kh       [40,48): vT   (dead after attn)
  // [48,56): ctxh      (dead after o-proj)
  // y_ws fp32 16MB over qh/kh [24,40) after attn; lg_ws over vT [40,..).
  ush* WoT_h = (ush*)(W8 + 0 * MB_);
  ush* WoT_l = (ush*)(W8 + 2 * MB_);
  ush* WqT_h = (ush*)(W8 + 4 * MB_);
  ush* WqT_l = (ush*)(W8 + 6 * MB_);
  ush* WkT_h = (ush*)(W8 + 8 * MB_);
  ush* WkT_l = (ush*)(W8 + 10 * MB_);
  ush* WvT_h = (ush*)(W8 + 12 * MB_);
  ush* WvT_l = (ush*)(W8 + 14 * MB_);
  ush* xh    = (ush*)(W8 + 16 * MB_);
  ush* qh    = (ush*)(W8 + 24 * MB_);
  ush* kh    = (ush*)(W8 + 32 * MB_);
  ush* vT    = (ush*)(W8 + 40 * MB_);
  ush* ctxh  = (ush*)(W8 + 48 * MB_);
  float* y_ws  = (float*)(W8 + 24 * MB_);  // over qh/kh (dead after attn)
  float* lg_ws = (float*)(W8 + 40 * MB_);  // over vT (dead after attn)

  split_wT4<<<dim3(16, 16, 4), 256, 0, stream>>>(
      Wq, Wk, Wv, Wo, WqT_h, WqT_l, WkT_h, WkT_l, WvT_h, WvT_l, WoT_h, WoT_l);
  cast_x<<<2048, 256, 0, stream>>>(x, xh);

  // Q+K+V fused: 768 blocks = 3/CU (48KB LDS x3 = 144KB fits).
  gemm_qkv<<<dim3(8, 32, 3), 256, 0, stream>>>(
      xh, WqT_h, WqT_l, WkT_h, WkT_l, WvT_h, WvT_l, bq, bk, bv, qh, kh, vT);
  attn2<<<dim3(16, 64), 256, 0, stream>>>(qh, kh, vT, ctxh);
  gemm_o<<<dim3(16, 32), 256, 0, stream>>>(ctxh, WoT_h, WoT_l, bo, x, y_ws);
  ln_span<<<4096, 256, 0, stream>>>(y_ws, ln_g, ln_b, Ws, bs, lg_ws);
  final_kernel<<<16, 256, 0, stream>>>(lg_ws, eb, out);
}

// Round 7
// 203.317 us; speedup vs baseline: 2.1023x; 1.2025x over previous
//
#include <hip/hip_runtime.h>
#include <hip/hip_bf16.h>
#include <math.h>

typedef unsigned short ush;
typedef __attribute__((ext_vector_type(8))) _Float16 fragh;  // 8 fp16 = 4 VGPRs
typedef __attribute__((ext_vector_type(4))) _Float16 half4;
typedef __attribute__((ext_vector_type(4))) float f32x4;

#define S_   1024
#define H_   1024
#define NH_  16
#define D_   64
#define L_   9
#define MB_  (1048576ull)

// async global->LDS, 16B per lane; lds ptr must be wave-uniform base.
__device__ __forceinline__ void load_lds16(const ush* g, const ush* l) {
  __builtin_amdgcn_global_load_lds(
      (const __attribute__((address_space(1))) void*)g,
      (__attribute__((address_space(3))) void*)l, 16, 0, 0);
}

// ---------------------------------------------------------------------------
// Cast + transpose 4 weights in one launch. W [k][n] fp32 -> WT [n][k] fp16.
// Grid (16,16,4). fp16 single precision is MORE accurate than the old
// bf16 h+l split consumed by a bf16 A (A-side error dominated).
// ---------------------------------------------------------------------------
__global__ __launch_bounds__(256) void cast_wT4(
    const float* W0, const float* W1, const float* W2, const float* W3,
    ush* T0, ush* T1, ush* T2, ush* T3) {
  __shared__ __align__(16) float Ls[64][68];
  const float* W = (blockIdx.z == 0) ? W0 : (blockIdx.z == 1) ? W1
                 : (blockIdx.z == 2) ? W2 : W3;
  ush* Th = (blockIdx.z == 0) ? T0 : (blockIdx.z == 1) ? T1
          : (blockIdx.z == 2) ? T2 : T3;
  const int tid = threadIdx.x;
  const int n0 = blockIdx.x * 64, k0 = blockIdx.y * 64;
#pragma unroll
  for (int it = 0; it < 4; it++) {
    int flat = tid + 256 * it;
    int row = flat >> 4, nc = (flat & 15) * 4;
    *(float4*)&Ls[row][nc] = *(const float4*)&W[(size_t)(k0 + row) * 1024 + n0 + nc];
  }
  __syncthreads();
#pragma unroll
  for (int it = 0; it < 2; it++) {
    int flat = tid + 256 * it;
    int nrow = flat >> 3, kc = (flat & 7) * 8;
    fragh v;
#pragma unroll
    for (int u = 0; u < 8; u++) v[u] = (_Float16)Ls[kc + u][nrow];
    *(fragh*)&Th[(size_t)(n0 + nrow) * 1024 + k0 + kc] = v;
  }
}

// ---------------------------------------------------------------------------
// Cast x: fp32 [4096x1024] -> fp16. Grid 2048.
// ---------------------------------------------------------------------------
__global__ __launch_bounds__(256) void cast_x(
    const float* __restrict__ x, ush* __restrict__ xh) {
  const size_t i = ((size_t)blockIdx.x * 256 + threadIdx.x) * 8;
  float4 a = *(const float4*)&x[i];
  float4 b = *(const float4*)&x[i + 4];
  fragh v;
  v[0] = (_Float16)a.x; v[1] = (_Float16)a.y;
  v[2] = (_Float16)a.z; v[3] = (_Float16)a.w;
  v[4] = (_Float16)b.x; v[5] = (_Float16)b.y;
  v[6] = (_Float16)b.z; v[7] = (_Float16)b.w;
  *(fragh*)&xh[i] = v;
}

// ---------------------------------------------------------------------------
// Fused QKV GEMM, fp16 single-term (m97 recipe: 16 MFMA / 8 ds_read_b128 /
// 4 stage-calls per wave per K-step). 128x128 tile, BK=32, double-buffered
// global_load_lds. z in {0,1,2} -> {Wq->qh, Wk->kh, Wv->vT transposed}.
// LDS 32KB. Grid (8,32,3) = 768 = 3/CU.
// ---------------------------------------------------------------------------
__global__ __launch_bounds__(256) void gemm_qkv(
    const ush* __restrict__ xh,
    const ush* __restrict__ Bq, const ush* __restrict__ Bk,
    const ush* __restrict__ Bv,
    const float* __restrict__ bq, const float* __restrict__ bk,
    const float* __restrict__ bv,
    ush* __restrict__ qh, ush* __restrict__ kh, ush* __restrict__ vT) {
  __shared__ __align__(16) ush As[2][128][32];   // [buf][m][k] fp16 bits
  __shared__ __align__(16) ush Bs[2][128][32];   // [buf][n][k] fp16 bits
  const int tid = threadIdx.x, lane = tid & 63, wave = tid >> 6;
  const int l15 = lane & 15, quad = lane >> 4;
  const int m0 = blockIdx.y * 128, n0 = blockIdx.x * 128;
  const int z = blockIdx.z;
  const ush* Bg = (z == 0) ? Bq : (z == 1) ? Bk : Bv;
  const float* bias = (z == 0) ? bq : (z == 1) ? bk : bv;
  ush* outp = (z == 0) ? qh : (z == 1) ? kh : vT;

  const int wm = (wave >> 1) * 64, wn = (wave & 1) * 64;

  f32x4 acc[4][4];
#pragma unroll
  for (int i = 0; i < 4; i++)
#pragma unroll
    for (int j = 0; j < 4; j++) acc[i][j] = (f32x4){0.f, 0.f, 0.f, 0.f};

  auto stage = [&](int bi, int k0) {
#pragma unroll
    for (int jj = 0; jj < 2; jj++) {          // A: 8 KB = 8 wave-calls
      const int call = wave * 2 + jj;
      const int c = call * 64 + lane;         // chunk in [0,512)
      const int r = c >> 2, ch = c & 3;
      load_lds16(xh + (size_t)(m0 + r) * 1024 + k0 + ch * 8,
                 &As[bi][0][0] + (size_t)call * 512);
    }
#pragma unroll
    for (int jj = 0; jj < 2; jj++) {          // B: 8 KB = 8 wave-calls
      const int call = wave * 2 + jj;
      const int c = call * 64 + lane;
      const int r = c >> 2, ch = c & 3;
      load_lds16(Bg + (size_t)(n0 + r) * 1024 + k0 + ch * 8,
                 &Bs[bi][0][0] + (size_t)call * 512);
    }
  };

  stage(0, 0);
  __syncthreads();

  for (int k0 = 0; k0 < 1024; k0 += 32) {
    const int cur = (k0 >> 5) & 1;
    if (k0 + 32 < 1024) stage(cur ^ 1, k0 + 32);

    fragh a[4], b[4];
#pragma unroll
    for (int s = 0; s < 4; s++)
      a[s] = *(const fragh*)&As[cur][wm + s * 16 + l15][quad * 8];
#pragma unroll
    for (int t = 0; t < 4; t++)
      b[t] = *(const fragh*)&Bs[cur][wn + t * 16 + l15][quad * 8];
#pragma unroll
    for (int mi = 0; mi < 4; mi++)
#pragma unroll
      for (int ni = 0; ni < 4; ni++)
        acc[mi][ni] = __builtin_amdgcn_mfma_f32_16x16x32_f16(
            a[mi], b[ni], acc[mi][ni], 0, 0, 0);
    __syncthreads();
  }

#pragma unroll
  for (int mi = 0; mi < 4; mi++) {
    const int rbase = m0 + wm + mi * 16 + quad * 4;
    const int bb = rbase >> 10, ss = rbase & 1023;
#pragma unroll
    for (int ni = 0; ni < 4; ni++) {
      const int col = n0 + wn + ni * 16 + l15;
      const float bv_ = bias[col];
      const int hidx = col >> 6, d = col & 63;
      if (z == 2) {
        // V: direct-transposed vT [bh][d][s], 4 consecutive s packed
        half4 p4;
        p4[0] = (_Float16)(acc[mi][ni][0] + bv_);
        p4[1] = (_Float16)(acc[mi][ni][1] + bv_);
        p4[2] = (_Float16)(acc[mi][ni][2] + bv_);
        p4[3] = (_Float16)(acc[mi][ni][3] + bv_);
        *(half4*)&outp[((size_t)(bb * NH_ + hidx) * D_ + d) * S_ + ss] = p4;
      } else {
#pragma unroll
        for (int r = 0; r < 4; r++) {
          const size_t o =
              ((size_t)(bb * NH_ + hidx) * S_ + (ss + r)) * D_ + d;
          *(_Float16*)&outp[o] = (_Float16)(acc[mi][ni][r] + bv_);
        }
      }
    }
  }
}

// ---------------------------------------------------------------------------
// O-projection GEMM: fp16 single-term. 128x64 tile; fp32 out + bias +
// residual. LDS 24KB. Grid (16,32) = 512 = 2/CU.
// ---------------------------------------------------------------------------
__global__ __launch_bounds__(256) void gemm_o(
    const ush* __restrict__ ctxh, const ush* __restrict__ Bo,
    const float* __restrict__ bo, const float* __restrict__ resid,
    float* __restrict__ outf) {
  __shared__ __align__(16) ush As[2][128][32];   // [buf][m][k]
  __shared__ __align__(16) ush Bs[2][64][32];    // [buf][n][k]
  const int tid = threadIdx.x, lane = tid & 63, wave = tid >> 6;
  const int l15 = lane & 15, quad = lane >> 4;
  const int m0 = blockIdx.y * 128, n0 = blockIdx.x * 64;
  const int wm = (wave >> 1) * 64, wn = (wave & 1) * 32;

  f32x4 acc[4][2];
#pragma unroll
  for (int i = 0; i < 4; i++)
#pragma unroll
    for (int j = 0; j < 2; j++) acc[i][j] = (f32x4){0.f, 0.f, 0.f, 0.f};

  auto stage = [&](int bi, int k0) {
#pragma unroll
    for (int jj = 0; jj < 2; jj++) {          // A: 8 wave-calls
      const int call = wave * 2 + jj;
      const int c = call * 64 + lane;
      const int r = c >> 2, ch = c & 3;
      load_lds16(ctxh + (size_t)(m0 + r) * 1024 + k0 + ch * 8,
                 &As[bi][0][0] + (size_t)call * 512);
    }
    {                                          // B: 4 wave-calls (1/wave)
      const int c = wave * 64 + lane;          // chunk in [0,256)
      const int r = c >> 2, ch = c & 3;
      load_lds16(Bo + (size_t)(n0 + r) * 1024 + k0 + ch * 8,
                 &Bs[bi][0][0] + (size_t)wave * 512);
    }
  };

  stage(0, 0);
  __syncthreads();

  for (int k0 = 0; k0 < 1024; k0 += 32) {
    const int cur = (k0 >> 5) & 1;
    if (k0 + 32 < 1024) stage(cur ^ 1, k0 + 32);

    fragh a[4], b[2];
#pragma unroll
    for (int s = 0; s < 4; s++)
      a[s] = *(const fragh*)&As[cur][wm + s * 16 + l15][quad * 8];
#pragma unroll
    for (int t = 0; t < 2; t++)
      b[t] = *(const fragh*)&Bs[cur][wn + t * 16 + l15][quad * 8];
#pragma unroll
    for (int mi = 0; mi < 4; mi++)
#pragma unroll
      for (int ni = 0; ni < 2; ni++)
        acc[mi][ni] = __builtin_amdgcn_mfma_f32_16x16x32_f16(
            a[mi], b[ni], acc[mi][ni], 0, 0, 0);
    __syncthreads();
  }

#pragma unroll
  for (int mi = 0; mi < 4; mi++) {
    const int rbase = m0 + wm + mi * 16 + quad * 4;
#pragma unroll
    for (int ni = 0; ni < 2; ni++) {
      const int col = n0 + wn + ni * 16 + l15;
      const float bv_ = bo[col];
#pragma unroll
      for (int r = 0; r < 4; r++) {
        const int m = rbase + r;
        outf[(size_t)m * 1024 + col] =
            acc[mi][ni][r] + bv_ + resid[(size_t)m * 1024 + col];
      }
    }
  }
}

// ---------------------------------------------------------------------------
// MFMA flash attention, fp16: Q,K,V,P all fp16 (more accurate than the
// passing bf16 version). Window |j0-q0| <= 128; LDS-LUT softmax with
// fixed shift M=2 (P in (0,~1]; fp16 denormal floor 6e-8 truncates only
// softmax weights < 1e-7 relative -- negligible). LDS ~28KB.
// ---------------------------------------------------------------------------
__global__ __launch_bounds__(256) void attn2(
    const ush* __restrict__ qh, const ush* __restrict__ kh,
    const ush* __restrict__ vT, ush* __restrict__ ch) {
  __shared__ __align__(16) ush Kh[64][72];
  __shared__ __align__(16) ush VTs[64][72];   // [d][j]
  __shared__ __align__(16) ush Pst[64][72];   // [m][j]
  __shared__ float LUT[256];
  const int tid = threadIdx.x;
  const int lane = tid & 63, wave = tid >> 6;
  const int l15 = lane & 15, quad = lane >> 4;
  const int w16 = wave * 16;
  const int bh = blockIdx.y;
  const int b = bh >> 4, h = bh & 15;
  const int q0 = blockIdx.x * 64;

  const float K1 = 0.18033688011112042f;   // 0.125 * log2(e)
  const float K2 = 0.14426950408889634f;   // 0.1   * log2(e)
  {
    const float dd = (float)tid;
    LUT[tid] = __expf(-0.1f * fminf(dd, 5.0f)) * K1 - dd * K2
             - 2.8853900817779268f;        // 2*log2(e): fixed shift M=2
  }

  const size_t qrow = ((size_t)bh * S_ + q0 + w16 + l15) * D_;
  fragh a_h[2];
  a_h[0] = *(const fragh*)&qh[qrow + quad * 8];
  a_h[1] = *(const fragh*)&qh[qrow + 32 + quad * 8];

  f32x4 o[4];
  float lrow[4];
#pragma unroll
  for (int i = 0; i < 4; i++) {
    o[i] = (f32x4){0.f, 0.f, 0.f, 0.f};
    lrow[i] = 0.f;
  }

  const size_t kbase = (size_t)bh * S_ * D_;
  const size_t vbase = (size_t)bh * D_ * S_;

  const int jlo = (q0 > 128) ? q0 - 128 : 0;
  const int jend = (q0 + 192 < S_) ? q0 + 192 : S_;

  for (int j0 = jlo; j0 < jend; j0 += 64) {
    __syncthreads();   // prior tile's frag reads done (also fences LUT)
#pragma unroll
    for (int it = 0; it < 2; it++) {
      const int flat = tid + 256 * it;
      const int row = flat >> 3, dc = (flat & 7) * 8;
      *(uint4*)&Kh[row][dc] =
          *(const uint4*)&kh[kbase + (size_t)(j0 + row) * D_ + dc];
      *(uint4*)&VTs[row][dc] =
          *(const uint4*)&vT[vbase + (size_t)row * S_ + j0 + dc];
    }
    __syncthreads();

    // ---- S = Q.K^T (single fp16 term) ----
    f32x4 c4[4];
#pragma unroll
    for (int nt = 0; nt < 4; nt++) c4[nt] = (f32x4){0.f, 0.f, 0.f, 0.f};
#pragma unroll
    for (int kk = 0; kk < 2; kk++) {
#pragma unroll
      for (int nt = 0; nt < 4; nt++) {
        fragh bh_ = *(const fragh*)&Kh[nt * 16 + l15][kk * 32 + quad * 8];
        c4[nt] = __builtin_amdgcn_mfma_f32_16x16x32_f16(a_h[kk], bh_, c4[nt], 0, 0, 0);
      }
    }

    // ---- LUT softmax + P store (C-layout: row=quad*4+r) ----
    const int ib = q0 + w16 + quad * 4 - j0 - l15;
#pragma unroll
    for (int r = 0; r < 4; r++) {
#pragma unroll
      for (int nt = 0; nt < 4; nt++) {
        int di = ib + r - nt * 16;
        di = (di < 0) ? -di : di;
        const float sv = exp2f(fmaf(c4[nt][r], K1, LUT[di]));
        lrow[r] += sv;
        *(_Float16*)&Pst[w16 + quad * 4 + r][nt * 16 + l15] = (_Float16)sv;
      }
    }

    // ---- PV (own rows only; same-wave LDS ordering, no barrier) ----
    fragh pa[2];
    pa[0] = *(const fragh*)&Pst[w16 + l15][quad * 8];
    pa[1] = *(const fragh*)&Pst[w16 + l15][32 + quad * 8];
#pragma unroll
    for (int dt = 0; dt < 4; dt++) {
      fragh vb0 = *(const fragh*)&VTs[dt * 16 + l15][quad * 8];
      fragh vb1 = *(const fragh*)&VTs[dt * 16 + l15][32 + quad * 8];
      o[dt] = __builtin_amdgcn_mfma_f32_16x16x32_f16(pa[0], vb0, o[dt], 0, 0, 0);
      o[dt] = __builtin_amdgcn_mfma_f32_16x16x32_f16(pa[1], vb1, o[dt], 0, 0, 0);
    }
  }

  // ---- deferred row-sum reduction + normalize + write fp16 ctx ----
#pragma unroll
  for (int r = 0; r < 4; r++) {
#pragma unroll
    for (int off = 1; off < 16; off <<= 1) lrow[r] += __shfl_xor(lrow[r], off);
    const float inv = 1.0f / lrow[r];
    const size_t rowp =
        ((size_t)(b * S_ + q0 + w16 + quad * 4 + r)) * H_ + h * 64;
#pragma unroll
    for (int dt = 0; dt < 4; dt++)
      *(_Float16*)&ch[rowp + dt * 16 + l15] = (_Float16)(o[dt][r] * inv);
  }
}

// ---------------------------------------------------------------------------
// Fused LayerNorm + span logits: one block per row. (verified R10)
// ---------------------------------------------------------------------------
__global__ __launch_bounds__(256) void ln_span(
    const float* __restrict__ y, const float* __restrict__ g,
    const float* __restrict__ bta, const float* __restrict__ Wsp,
    const float* __restrict__ bs, float* __restrict__ logits) {
  const int row = blockIdx.x;
  const int tid = threadIdx.x, lane = tid & 63, wave = tid >> 6;
  const float* yr = y + (size_t)row * 1024;
  float vals[4], s = 0.f, s2 = 0.f;
#pragma unroll
  for (int i = 0; i < 4; i++) {
    float t = yr[tid + i * 256];
    vals[i] = t; s += t; s2 += t * t;
  }
#pragma unroll
  for (int off = 32; off; off >>= 1) {
    s += __shfl_xor(s, off);
    s2 += __shfl_xor(s2, off);
  }
  __shared__ float red[8];
  __shared__ float red9[4][12];
  if (lane == 0) { red[wave] = s; red[4 + wave] = s2; }
  __syncthreads();
  s = red[0] + red[1] + red[2] + red[3];
  s2 = red[4] + red[5] + red[6] + red[7];
  const float mu = s * (1.0f / 1024.0f);
  const float var = s2 * (1.0f / 1024.0f) - mu * mu;
  const float inv = rsqrtf(var + 1e-5f);

  float lg[9];
#pragma unroll
  for (int l = 0; l < 9; l++) lg[l] = 0.f;
#pragma unroll
  for (int i = 0; i < 4; i++) {
    const int hh = tid + i * 256;
    const float yn = (vals[i] - mu) * inv * g[hh] + bta[hh];
#pragma unroll
    for (int l = 0; l < 9; l++) lg[l] += yn * Wsp[hh * 9 + l];
  }
#pragma unroll
  for (int l = 0; l < 9; l++) {
#pragma unroll
    for (int off = 32; off; off >>= 1) lg[l] += __shfl_xor(lg[l], off);
  }
  if (lane == 0) {
#pragma unroll
    for (int l = 0; l < 9; l++) red9[wave][l] = lg[l];
  }
  __syncthreads();
  if (tid < 9) {
    logits[(size_t)row * 9 + tid] =
        red9[0][tid] + red9[1][tid] + red9[2][tid] + red9[3][tid] + bs[tid];
  }
}

// ---------------------------------------------------------------------------
// Entity-bias adjustment + FP32 output. One thread per token.
// ---------------------------------------------------------------------------
__global__ __launch_bounds__(256) void final_kernel(
    const float* __restrict__ logits, const float* __restrict__ eb,
    float* __restrict__ out) {
  const int m = blockIdx.x * 256 + threadIdx.x;
  const int i = m & 1023;
  float cur[9];
#pragma unroll
  for (int l = 0; l < 9; l++) cur[l] = logits[(size_t)m * 9 + l];
  if (i > 0) {
    const float* prev = logits + (size_t)(m - 1) * 9;
    int am = 0;
    float best = prev[0];
#pragma unroll
    for (int l = 1; l < 9; l++) {
      float pv = prev[l];
      if (pv > best) { best = pv; am = l; }
    }
    if (am == 1) cur[2] += 2.0f * eb[2];
  }
#pragma unroll
  for (int l = 0; l < 9; l++) out[(size_t)m * 9 + l] = cur[l];
}

// ---------------------------------------------------------------------------
extern "C" void kernel_launch(void* const* d_in, const int* in_sizes, int n_in,
                              void* d_out, int out_size, void* d_ws, size_t ws_size,
                              hipStream_t stream) {
  const float* x    = (const float*)d_in[0];
  const float* Wq   = (const float*)d_in[1];
  const float* bq   = (const float*)d_in[2];
  const float* Wk   = (const float*)d_in[3];
  const float* bk   = (const float*)d_in[4];
  const float* Wv   = (const float*)d_in[5];
  const float* bv   = (const float*)d_in[6];
  const float* Wo   = (const float*)d_in[7];
  const float* bo   = (const float*)d_in[8];
  const float* ln_g = (const float*)d_in[9];
  const float* ln_b = (const float*)d_in[10];
  const float* Ws   = (const float*)d_in[11];
  const float* bs   = (const float*)d_in[12];
  const float* eb   = (const float*)d_in[13];
  float* out = (float*)d_out;
  char* W8 = (char*)d_ws;

  // ---- ws layout (fp16 everywhere; 64 MB envelope) ----
  // [0,2):   WoT      (alive until o-proj)
  // [2,4):   WqT  [4,6): WkT  [6,8): WvT   (dead after qkv)
  // [8,16):  xh       (dead after qkv)
  // [16,24): qh  [24,32): kh  [32,40): vT  (dead after attn)
  // [40,48): ctxh     (dead after o-proj)
  // [48,64): y_ws fp32
  // lg_ws over qh [16,..) after attn (147KB).
  ush* WoT  = (ush*)(W8 + 0 * MB_);
  ush* WqT  = (ush*)(W8 + 2 * MB_);
  ush* WkT  = (ush*)(W8 + 4 * MB_);
  ush* WvT  = (ush*)(W8 + 6 * MB_);
  ush* xh   = (ush*)(W8 + 8 * MB_);
  ush* qh   = (ush*)(W8 + 16 * MB_);
  ush* kh   = (ush*)(W8 + 24 * MB_);
  ush* vT   = (ush*)(W8 + 32 * MB_);
  ush* ctxh = (ush*)(W8 + 40 * MB_);
  float* y_ws  = (float*)(W8 + 48 * MB_);
  float* lg_ws = (float*)(W8 + 16 * MB_);  // over qh (dead after attn)

  cast_wT4<<<dim3(16, 16, 4), 256, 0, stream>>>(
      Wq, Wk, Wv, Wo, WqT, WkT, WvT, WoT);
  cast_x<<<2048, 256, 0, stream>>>(x, xh);

  // Q+K+V fused: 768 blocks = 3/CU, 32KB LDS.
  gemm_qkv<<<dim3(8, 32, 3), 256, 0, stream>>>(
      xh, WqT, WkT, WvT, bq, bk, bv, qh, kh, vT);
  attn2<<<dim3(16, 64), 256, 0, stream>>>(qh, kh, vT, ctxh);
  gemm_o<<<dim3(16, 32), 256, 0, stream>>>(ctxh, WoT, bo, x, y_ws);
  ln_span<<<4096, 256, 0, stream>>>(y_ws, ln_g, ln_b, Ws, bs, lg_ws);
  final_kernel<<<16, 256, 0, stream>>>(lg_ws, eb, out);
}